// Round 1
// 1072.092 us; speedup vs baseline: 1.1382x; 1.1382x over previous
//
#include <hip/hip_runtime.h>
#include <hip/hip_fp16.h>

// Journal:
// R1: full pipeline, MFMA everywhere -> out0 err 0.59; out1 structurally wrong.
// R2: out1 fixed; post-pool all-f32 -> err bit-identical 0.59375.
// R3: dtype-detector theory -> flag=0 (f32 inputs), no change. Wrong theory.
// R4: REAL BUG: log_softmax subtracted m twice. PASSED, absmax 0.0078,
//     dur 6543us. Profile: sgemm_simple 2x3030us (VALUBusy 0.25%, occ 3%) =
//     latency-bound serial-K naive GEMM.
// R5: att-MLP + lin1 back on MFMA gemm_bt (R1 structure): Wt3/Wt4 bf16 B^T,
//     A3 bf16 384xKATT (320 used), A4 bf16 128xKATT (64 used). evF stays f32
//     for the softmax-weighted graph accumulation. 6543 -> 1220us.
// R6: rocprof top-5 = detect_kernel x5 @181us (1 active lane, serial 6144
//     loads, VALUBusy 0.019%). Wave-parallelize detector: 64 lanes, coalesced
//     strided scan + __shfl_down reduce. Predict detect 181 -> <5us,
//     total 1220 -> ~1045us. Semantics identical (order-independent counts).

#define BN 64
#define EVI 5
#define SEQS (BN * EVI)
#define LSEQ 256
#define DIM 768
#define WORDS 32
#define TPW 4
#define NNODE (BN * EVI * WORDS)   // 10240
#define NEDGE (NNODE * 16)         // 163840
#define RREL 4
#define DOUT 768
#define LH 1024
#define NCLS 3
#define KBIG (5 * DIM)             // 3840
#define KATT (DIM + 2 * DOUT)      // 2304

typedef float f32x4 __attribute__((ext_vector_type(4)));
typedef __bf16 bf16x8 __attribute__((ext_vector_type(8)));

__device__ inline unsigned short f2bf(float f) {
    union { float f; unsigned int u; } v; v.f = f;
    unsigned int u = v.u;
    unsigned int lsb = (u >> 16) & 1u;
    u += 0x7fffu + lsb;
    return (unsigned short)(u >> 16);
}
__device__ inline float bf2f(unsigned short h) {
    union { float f; unsigned int u; } v; v.u = ((unsigned int)h) << 16; return v.f;
}

// flag: 0 = f32, 1 = fp16, 2 = bf16 storage of "float32" inputs
__device__ inline float ldin(const void* p, long i, int f) {
    if (f == 1) return __half2float(((const __half*)p)[i]);
    if (f == 2) return bf2f(((const unsigned short*)p)[i]);
    return ((const float*)p)[i];
}

// ---------------- dtype detector (no-op safety; R3 showed flag=0) ----------
// R6: wave-parallel. 64 lanes, coalesced strided loads, shfl reduction.
__global__ void detect_kernel(const void* w, int* flag) {
    if (blockIdx.x != 0) return;
    const int lane = threadIdx.x;           // block of 64 = one wave
    const unsigned int* u32 = (const unsigned int*)w;
    const unsigned short* u16 = (const unsigned short*)w;
    int tiny = 0;
    for (int i = lane; i < 2048; i += 64) {
        unsigned int b = u32[i];
        float f; __builtin_memcpy(&f, &b, 4);
        float a = fabsf(f);
        if (!(a > 1e-10f)) tiny++;
    }
    int band = 0;
    for (int i = lane; i < 4096; i += 64) {
        unsigned short h = u16[i];
        int e8 = (h >> 7) & 0xFF;
        if (h == 0 || (e8 >= 0x66 && e8 <= 0x86)) band++;
    }
#pragma unroll
    for (int o = 32; o > 0; o >>= 1) {
        tiny += __shfl_down(tiny, o);
        band += __shfl_down(band, o);
    }
    if (lane == 0) {
        if (tiny > 1024) { *flag = 1; return; }
        *flag = (band > 3900) ? 2 : 0;
    }
}

// ---------------- canonicalize a float input to f32 ----------------
__global__ void convert_kernel(const void* __restrict__ src, float* __restrict__ dst,
                               long n, const int* __restrict__ flag)
{
    int f = *flag;
    long stride = (long)gridDim.x * 256;
    for (long i = (long)blockIdx.x * 256 + threadIdx.x; i < n; i += stride)
        dst[i] = ldin(src, i, f);
}

// ---------------- token gather + mean over TPW ----------------
__global__ __launch_bounds__(256) void gather_mean_kernel(
    const void* __restrict__ tok, const int* __restrict__ widx,
    unsigned short* __restrict__ xb, const int* __restrict__ flag)
{
    int f = *flag;
    int n = blockIdx.x;
    long i0 = widx[n * 4 + 0], i1 = widx[n * 4 + 1];
    long i2 = widx[n * 4 + 2], i3 = widx[n * 4 + 3];
    for (int c = threadIdx.x; c < DIM; c += 256) {
        float s = ldin(tok, i0 * DIM + c, f) + ldin(tok, i1 * DIM + c, f)
                + ldin(tok, i2 * DIM + c, f) + ldin(tok, i3 * DIM + c, f);
        xb[(long)n * DIM + c] = f2bf(s * 0.25f);
    }
}

// ---------------- edge prep ----------------
__global__ void count_kernel(const int* __restrict__ ei, const int* __restrict__ et,
                             int* __restrict__ cnt)
{
    int e = blockIdx.x * 256 + threadIdx.x;
    if (e >= NEDGE) return;
    int dst = ei[NEDGE + e];
    int r = et[e];
    atomicAdd(&cnt[dst * RREL + r], 1);
}

__global__ __launch_bounds__(1024) void scan_kernel(const int* __restrict__ cnt,
                                                    int* __restrict__ offs, int n)
{
    __shared__ int buf[1024];
    __shared__ int carry;
    int tid = threadIdx.x;
    if (tid == 0) { carry = 0; offs[0] = 0; }
    __syncthreads();
    for (int base = 0; base < n; base += 1024) {
        int v = (base + tid < n) ? cnt[base + tid] : 0;
        buf[tid] = v;
        __syncthreads();
        for (int o = 1; o < 1024; o <<= 1) {
            int t = (tid >= o) ? buf[tid - o] : 0;
            __syncthreads();
            buf[tid] += t;
            __syncthreads();
        }
        if (base + tid < n) offs[base + tid + 1] = carry + buf[tid];
        __syncthreads();
        if (tid == 0) carry += buf[1023];
        __syncthreads();
    }
}

__global__ void fill_kernel(const int* __restrict__ ei, const int* __restrict__ et,
                            const int* __restrict__ offs, int* __restrict__ cursor,
                            int* __restrict__ sorted)
{
    int e = blockIdx.x * 256 + threadIdx.x;
    if (e >= NEDGE) return;
    int src = ei[e];
    int dst = ei[NEDGE + e];
    int r = et[e];
    int seg = dst * RREL + r;
    int pos = offs[seg] + atomicAdd(&cursor[seg], 1);
    sorted[pos] = src;
}

// ---------------- segment aggregation (per node) ----------------
__global__ __launch_bounds__(256) void aggregate_kernel(
    const unsigned short* __restrict__ xsrc, long xstride,
    const int* __restrict__ offs, const int* __restrict__ sorted,
    unsigned short* __restrict__ A, int write_root)
{
    int n = blockIdx.x;
    long base = (long)n * KBIG;
    for (int r = 0; r < RREL; r++) {
        int s0 = offs[n * RREL + r], s1 = offs[n * RREL + r + 1];
        float inv = 1.0f / (float)max(s1 - s0, 1);
        for (int c = threadIdx.x; c < DIM; c += 256) {
            float acc = 0.0f;
            for (int i = s0; i < s1; i++) {
                long s = sorted[i];
                acc += bf2f(xsrc[s * xstride + c]);
            }
            A[base + r * DIM + c] = f2bf(acc * inv);
        }
    }
    if (write_root) {
        for (int c = threadIdx.x; c < DIM; c += 256)
            A[base + 4 * DIM + c] = xsrc[(long)n * xstride + c];
    }
}

// ---------------- transpose + cast f32 -> bf16 ----------------
__global__ __launch_bounds__(256) void transpose_cast_kernel(
    const float* __restrict__ in, int Ncols,
    unsigned short* __restrict__ out, int outStride, int colOff)
{
    __shared__ float t[32][33];
    int kt = blockIdx.x * 32, nt = blockIdx.y * 32;
    int lx = threadIdx.x & 31, ly = threadIdx.x >> 5;
    for (int i = 0; i < 4; i++)
        t[ly + i * 8][lx] = in[(long)(kt + ly + i * 8) * Ncols + nt + lx];
    __syncthreads();
    for (int i = 0; i < 4; i++)
        out[(long)(nt + ly + i * 8) * outStride + colOff + kt + lx] = f2bf(t[lx][ly + i * 8]);
}

// ---------------- MFMA GEMM: C = A (M,K) @ Bt^T, bf16 in, f32 acc --------
__global__ __launch_bounds__(256) void gemm_bt_kernel(
    const unsigned short* __restrict__ A, const unsigned short* __restrict__ Bt,
    int K, const float* __restrict__ bias, int relu,
    float* __restrict__ outF, long strideF,
    unsigned short* __restrict__ outB, long strideB)
{
    __shared__ __align__(16) unsigned short As[128 * 32];
    __shared__ __align__(16) unsigned short Bs[128 * 32];
    const int tid = threadIdx.x;
    const int lane = tid & 63, wv = tid >> 6;
    const int wr = wv >> 1, wc = wv & 1;
    const int lr = lane & 15, q = lane >> 4;
    const long m0 = (long)blockIdx.x * 128, n0 = (long)blockIdx.y * 128;

    f32x4 acc[4][4] = {};

    for (int kt = 0; kt < K; kt += 32) {
#pragma unroll
        for (int i = 0; i < 2; i++) {
            int chunk = i * 256 + tid;
            int row = chunk >> 2, kc = (chunk & 3) * 8;
            const unsigned short* ga = A + (m0 + row) * K + kt + kc;
            const unsigned short* gb = Bt + (n0 + row) * K + kt + kc;
            int ldsbase = (i * 256 + wv * 64) * 8;
            __builtin_amdgcn_global_load_lds(
                (const __attribute__((address_space(1))) void*)ga,
                (__attribute__((address_space(3))) void*)&As[ldsbase], 16, 0, 0);
            __builtin_amdgcn_global_load_lds(
                (const __attribute__((address_space(1))) void*)gb,
                (__attribute__((address_space(3))) void*)&Bs[ldsbase], 16, 0, 0);
        }
        __syncthreads();
        bf16x8 af[4], bfr[4];
#pragma unroll
        for (int i = 0; i < 4; i++)
            af[i] = *(const bf16x8*)&As[(wr * 64 + i * 16 + lr) * 32 + q * 8];
#pragma unroll
        for (int j = 0; j < 4; j++)
            bfr[j] = *(const bf16x8*)&Bs[(wc * 64 + j * 16 + lr) * 32 + q * 8];
#pragma unroll
        for (int i = 0; i < 4; i++)
#pragma unroll
            for (int j = 0; j < 4; j++)
                acc[i][j] = __builtin_amdgcn_mfma_f32_16x16x32_bf16(af[i], bfr[j], acc[i][j], 0, 0, 0);
        __syncthreads();
    }

#pragma unroll
    for (int i = 0; i < 4; i++) {
#pragma unroll
        for (int j = 0; j < 4; j++) {
            long col = n0 + wc * 64 + j * 16 + lr;
            float bv = bias ? bias[col] : 0.0f;
#pragma unroll
            for (int r = 0; r < 4; r++) {
                long row = m0 + wr * 64 + i * 16 + q * 4 + r;
                float v = acc[i][j][r] + bv;
                if (relu) v = fmaxf(v, 0.0f);
                if (outF) outF[row * strideF + col] = v;
                if (outB) outB[row * strideB + col] = f2bf(v);
            }
        }
    }
}

// ---------------- pooling (mean/max over words) + cc -> bf16 A3 + f32 evF ----
__global__ __launch_bounds__(256) void pool_cc_kernel(
    const float* __restrict__ C2, const void* __restrict__ tok,
    const int* __restrict__ csi, unsigned short* __restrict__ A3,
    float* __restrict__ evF, const int* __restrict__ flag)
{
    int f = *flag;
    int s = blockIdx.x;
    int b = s / EVI;
    long seq = csi[b];
    for (int c = threadIdx.x; c < DIM; c += 256) {
        float mx = -1e30f, sm = 0.0f;
        const float* col = C2 + (long)s * WORDS * DOUT + c;
        for (int w = 0; w < WORDS; w++) {
            float v = col[(long)w * DOUT];
            sm += v;
            mx = fmaxf(mx, v);
        }
        float mean = sm * (1.0f / WORDS);
        evF[(long)s * (2 * DOUT) + c] = mean;
        evF[(long)s * (2 * DOUT) + DOUT + c] = mx;
        A3[(long)s * KATT + c] = f2bf(ldin(tok, seq * LSEQ * DIM + c, f));
        A3[(long)s * KATT + DIM + c] = f2bf(mean);
        A3[(long)s * KATT + DIM + DOUT + c] = f2bf(mx);
    }
}

// ---------------- p = h @ att_w1 ----------------
__global__ __launch_bounds__(256) void pdot_kernel(
    const float* __restrict__ h, const float* __restrict__ w1, float* __restrict__ p)
{
    int i = blockIdx.x;
    float s = 0.0f;
    for (int k = threadIdx.x; k < DOUT; k += 256) s += h[(long)i * DOUT + k] * w1[k];
    __shared__ float red[256];
    red[threadIdx.x] = s;
    __syncthreads();
    for (int o = 128; o > 0; o >>= 1) {
        if (threadIdx.x < o) red[threadIdx.x] += red[threadIdx.x + o];
        __syncthreads();
    }
    if (threadIdx.x == 0) p[i] = red[0];
}

// ---------------- attention output: sigmoid(p[i]) for all 320 rows ----------
__global__ void att_out_kernel(const float* __restrict__ p, float* __restrict__ out)
{
    int i = blockIdx.x * 256 + threadIdx.x;
    if (i < SEQS) out[BN * NCLS + i] = 1.0f / (1.0f + __expf(-p[i]));
}

// ---------------- softmax over EVI + weighted ev + build A4 (bf16) ----------
__global__ __launch_bounds__(256) void softgraph_kernel(
    const float* __restrict__ p, const float* __restrict__ evF,
    const float* __restrict__ ccls, unsigned short* __restrict__ A4)
{
    int b = blockIdx.x;
    __shared__ float a[EVI];
    if (threadIdx.x == 0) {
        float m = -1e30f;
        for (int e = 0; e < EVI; e++) m = fmaxf(m, p[b * EVI + e]);
        float s = 0.0f, ex[EVI];
        for (int e = 0; e < EVI; e++) { ex[e] = __expf(p[b * EVI + e] - m); s += ex[e]; }
        for (int e = 0; e < EVI; e++) a[e] = ex[e] / s;
    }
    __syncthreads();
    for (int d = threadIdx.x; d < 2 * DOUT; d += 256) {
        float g = 0.0f;
        for (int e = 0; e < EVI; e++)
            g += a[e] * evF[(long)(b * EVI + e) * (2 * DOUT) + d];
        A4[(long)b * KATT + d] = f2bf(g);
    }
    for (int c = threadIdx.x; c < DIM; c += 256)
        A4[(long)b * KATT + 2 * DOUT + c] = f2bf(ccls[(long)b * DIM + c]);
}

// ---------------- final: lin2 + log_softmax ----------------
__global__ __launch_bounds__(256) void final_kernel(
    const float* __restrict__ C4, const float* __restrict__ w2,
    const float* __restrict__ bb, float* __restrict__ out)
{
    int b = blockIdx.x;
    float s0 = 0.0f, s1 = 0.0f, s2 = 0.0f;
    for (int k = threadIdx.x; k < LH; k += 256) {
        float h = C4[(long)b * LH + k];
        s0 += h * w2[k * NCLS + 0];
        s1 += h * w2[k * NCLS + 1];
        s2 += h * w2[k * NCLS + 2];
    }
    __shared__ float r0[256], r1[256], r2[256];
    int t = threadIdx.x;
    r0[t] = s0; r1[t] = s1; r2[t] = s2;
    __syncthreads();
    for (int o = 128; o > 0; o >>= 1) {
        if (t < o) { r0[t] += r0[t + o]; r1[t] += r1[t + o]; r2[t] += r2[t + o]; }
        __syncthreads();
    }
    if (t == 0) {
        float l0 = r0[0] + bb[0], l1 = r1[0] + bb[1], l2 = r2[0] + bb[2];
        float m = fmaxf(l0, fmaxf(l1, l2));
        float lse = logf(__expf(l0 - m) + __expf(l1 - m) + __expf(l2 - m)) + m;
        out[b * NCLS + 0] = l0 - lse;
        out[b * NCLS + 1] = l1 - lse;
        out[b * NCLS + 2] = l2 - lse;
    }
}

extern "C" void kernel_launch(void* const* d_in, const int* in_sizes, int n_in,
                              void* d_out, int out_size, void* d_ws, size_t ws_size,
                              hipStream_t stream)
{
    const void* tok      = d_in[0];
    const void* ccls_r   = d_in[1];
    const void* W_rel1_r = d_in[2];
    const void* W_root1_r= d_in[3];
    const void* b1_r     = d_in[4];
    const void* W_rel2_r = d_in[5];
    const void* W_root2_r= d_in[6];
    const void* b2_r     = d_in[7];
    const void* att_w0_r = d_in[8];
    const void* att_w1_r = d_in[9];
    const void* lin1_w_r = d_in[10];
    const void* lin1_b_r = d_in[11];
    const void* lin2_w_r = d_in[12];
    const void* lin2_b_r = d_in[13];
    const int* widx      = (const int*)d_in[14];
    const int* ei        = (const int*)d_in[15];
    const int* et        = (const int*)d_in[16];
    const int* csi       = (const int*)d_in[17];
    float* out           = (float*)d_out;

    char* ws = (char*)d_ws;
    size_t off = 0;
    auto alloc = [&](size_t bytes) { size_t o = off; off = (off + bytes + 255) & ~(size_t)255; return o; };

    int* flag   = (int*)(ws + alloc(256));
    float* cclsF   = (float*)(ws + alloc((size_t)BN * DIM * 4));
    float* Wrel1F  = (float*)(ws + alloc((size_t)RREL * DIM * DIM * 4));
    float* Wroot1F = (float*)(ws + alloc((size_t)DIM * DIM * 4));
    float* b1F     = (float*)(ws + alloc((size_t)DIM * 4));
    float* Wrel2F  = (float*)(ws + alloc((size_t)RREL * DIM * DOUT * 4));
    float* Wroot2F = (float*)(ws + alloc((size_t)DIM * DOUT * 4));
    float* b2F     = (float*)(ws + alloc((size_t)DOUT * 4));
    float* aw0F    = (float*)(ws + alloc((size_t)KATT * DOUT * 4));
    float* aw1F    = (float*)(ws + alloc((size_t)DOUT * 4));
    float* l1wF    = (float*)(ws + alloc((size_t)KATT * LH * 4));
    float* l1bF    = (float*)(ws + alloc((size_t)LH * 4));
    float* l2wF    = (float*)(ws + alloc((size_t)LH * NCLS * 4));
    float* l2bF    = (float*)(ws + alloc((size_t)NCLS * 4));
    unsigned short* xb  = (unsigned short*)(ws + alloc((size_t)NNODE * DIM * 2));
    unsigned short* A1  = (unsigned short*)(ws + alloc((size_t)NNODE * KBIG * 2));
    unsigned short* X1  = (unsigned short*)(ws + alloc((size_t)NNODE * DOUT * 2));
    unsigned short* Wt1 = (unsigned short*)(ws + alloc((size_t)DIM * KBIG * 2));
    unsigned short* Wt2 = (unsigned short*)(ws + alloc((size_t)DIM * KBIG * 2));
    unsigned short* Wt3 = (unsigned short*)(ws + alloc((size_t)DOUT * KATT * 2));
    unsigned short* Wt4 = (unsigned short*)(ws + alloc((size_t)LH * KATT * 2));
    float* C2           = (float*)(ws + alloc((size_t)NNODE * DOUT * 4));
    unsigned short* A3  = (unsigned short*)(ws + alloc((size_t)384 * KATT * 2));
    float* C3           = (float*)(ws + alloc((size_t)384 * DOUT * 4));
    float* evF          = (float*)(ws + alloc((size_t)SEQS * 2 * DOUT * 4));
    float* pbuf         = (float*)(ws + alloc((size_t)SEQS * 4));
    unsigned short* A4  = (unsigned short*)(ws + alloc((size_t)128 * KATT * 2));
    float* C4           = (float*)(ws + alloc((size_t)128 * LH * 4));
    int* cnt            = (int*)(ws + alloc((size_t)2 * NNODE * RREL * 4));
    int* cursor         = cnt + NNODE * RREL;
    int* offs           = (int*)(ws + alloc((size_t)(NNODE * RREL + 1) * 4));
    int* sorted         = (int*)(ws + alloc((size_t)NEDGE * 4));
    (void)ws_size; (void)in_sizes; (void)n_in; (void)out_size;

    // dtype detect + canonicalize (flag=0 path verified by R3)
    detect_kernel<<<1, 64, 0, stream>>>(W_rel1_r, flag);
    auto conv = [&](const void* src, float* dst, long n) {
        int grid = (int)min((n + 255) / 256, (long)2048);
        convert_kernel<<<grid, 256, 0, stream>>>(src, dst, n, flag);
    };
    conv(ccls_r,   cclsF,   (long)BN * DIM);
    conv(W_rel1_r, Wrel1F,  (long)RREL * DIM * DIM);
    conv(W_root1_r,Wroot1F, (long)DIM * DIM);
    conv(b1_r,     b1F,     DIM);
    conv(W_rel2_r, Wrel2F,  (long)RREL * DIM * DOUT);
    conv(W_root2_r,Wroot2F, (long)DIM * DOUT);
    conv(b2_r,     b2F,     DOUT);
    conv(att_w0_r, aw0F,    (long)KATT * DOUT);
    conv(att_w1_r, aw1F,    DOUT);
    conv(lin1_w_r, l1wF,    (long)KATT * LH);
    conv(lin1_b_r, l1bF,    LH);
    conv(lin2_w_r, l2wF,    (long)LH * NCLS);
    conv(lin2_b_r, l2bF,    NCLS);

    // edge prep
    hipMemsetAsync(cnt, 0, (size_t)2 * NNODE * RREL * 4, stream);
    count_kernel<<<NEDGE / 256, 256, 0, stream>>>(ei, et, cnt);
    scan_kernel<<<1, 1024, 0, stream>>>(cnt, offs, NNODE * RREL);
    fill_kernel<<<NEDGE / 256, 256, 0, stream>>>(ei, et, offs, cursor, sorted);

    // token gather
    gather_mean_kernel<<<NNODE, 256, 0, stream>>>(tok, widx, xb, flag);

    // weight transposes (f32 -> bf16, B^T layout)
    transpose_cast_kernel<<<dim3(96, 24), 256, 0, stream>>>(Wrel1F, DIM, Wt1, KBIG, 0);
    transpose_cast_kernel<<<dim3(24, 24), 256, 0, stream>>>(Wroot1F, DIM, Wt1, KBIG, 4 * DIM);
    transpose_cast_kernel<<<dim3(96, 24), 256, 0, stream>>>(Wrel2F, DOUT, Wt2, KBIG, 0);
    transpose_cast_kernel<<<dim3(24, 24), 256, 0, stream>>>(Wroot2F, DOUT, Wt2, KBIG, 4 * DIM);
    transpose_cast_kernel<<<dim3(72, 24), 256, 0, stream>>>(aw0F, DOUT, Wt3, KATT, 0);
    transpose_cast_kernel<<<dim3(72, 32), 256, 0, stream>>>(l1wF, LH, Wt4, KATT, 0);

    // layer 1: A1 = [agg_r(xb) | xb];  X1 = relu(A1 @ W1)
    aggregate_kernel<<<NNODE, 256, 0, stream>>>(xb, DIM, offs, sorted, A1, 1);
    gemm_bt_kernel<<<dim3(NNODE / 128, DIM / 128), 256, 0, stream>>>(
        A1, Wt1, KBIG, b1F, 1, nullptr, 0, X1, DOUT);

    // layer 2: A1 = [agg_r(X1) | X1];  C2 = relu(A1 @ W2)  (f32)
    aggregate_kernel<<<NNODE, 256, 0, stream>>>(X1, DOUT, offs, sorted, A1, 1);
    gemm_bt_kernel<<<dim3(NNODE / 128, DOUT / 128), 256, 0, stream>>>(
        A1, Wt2, KBIG, b2F, 1, C2, DOUT, nullptr, 0);

    // pooling + attention MLP (MFMA)
    pool_cc_kernel<<<SEQS, 256, 0, stream>>>(C2, tok, csi, A3, evF, flag);
    gemm_bt_kernel<<<dim3(3, DOUT / 128), 256, 0, stream>>>(
        A3, Wt3, KATT, nullptr, 1, C3, DOUT, nullptr, 0);
    pdot_kernel<<<SEQS, 256, 0, stream>>>(C3, aw1F, pbuf);
    att_out_kernel<<<(SEQS + 255) / 256, 256, 0, stream>>>(pbuf, out);
    softgraph_kernel<<<BN, 256, 0, stream>>>(pbuf, evF, cclsF, A4);

    // classifier head (MFMA)
    gemm_bt_kernel<<<dim3(1, LH / 128), 256, 0, stream>>>(
        A4, Wt4, KATT, l1bF, 1, C4, LH, nullptr, 0);
    final_kernel<<<BN, 256, 0, stream>>>(C4, l2wF, l2bF, out);
}

// Round 2
// 1058.291 us; speedup vs baseline: 1.1531x; 1.0130x over previous
//
#include <hip/hip_runtime.h>
#include <hip/hip_fp16.h>

// Journal:
// R1: full pipeline, MFMA everywhere -> out0 err 0.59; out1 structurally wrong.
// R2: out1 fixed; post-pool all-f32 -> err bit-identical 0.59375.
// R3: dtype-detector theory -> flag=0 (f32 inputs), no change. Wrong theory.
// R4: REAL BUG: log_softmax subtracted m twice. PASSED, absmax 0.0078,
//     dur 6543us. Profile: sgemm_simple 2x3030us (VALUBusy 0.25%, occ 3%) =
//     latency-bound serial-K naive GEMM.
// R5: att-MLP + lin1 back on MFMA gemm_bt: 6543 -> 1220us.
// R6: wave-parallel detect (was 1 lane, 181us serial): 1220 -> 1072us.
//     Prediction matched (-148 vs -176 predicted).
// R7: top-5 now all harness fillBuffer @149us (workspace re-poison, 84% HBM,
//     not ours, masks our kernels => no kernel of ours >148us). This round:
//     (a) kill 10/13 convert launches - decode raw weights directly in
//         transpose_cast/softgraph/pdot/final via ldin+flag (~80MB HBM +
//         ~20us launch overhead saved);
//     (b) scan_kernel was ~800 barrier-rounds on 1 CU (Hillis-Steele x40
//         outer): thread-coarsened 2-pass scan, ~22 barriers.
//     Predict 1072 -> ~980us. absmax unchanged (same bf16 rounding).

#define BN 64
#define EVI 5
#define SEQS (BN * EVI)
#define LSEQ 256
#define DIM 768
#define WORDS 32
#define TPW 4
#define NNODE (BN * EVI * WORDS)   // 10240
#define NEDGE (NNODE * 16)         // 163840
#define RREL 4
#define DOUT 768
#define LH 1024
#define NCLS 3
#define KBIG (5 * DIM)             // 3840
#define KATT (DIM + 2 * DOUT)      // 2304

typedef float f32x4 __attribute__((ext_vector_type(4)));
typedef __bf16 bf16x8 __attribute__((ext_vector_type(8)));

__device__ inline unsigned short f2bf(float f) {
    union { float f; unsigned int u; } v; v.f = f;
    unsigned int u = v.u;
    unsigned int lsb = (u >> 16) & 1u;
    u += 0x7fffu + lsb;
    return (unsigned short)(u >> 16);
}
__device__ inline float bf2f(unsigned short h) {
    union { float f; unsigned int u; } v; v.u = ((unsigned int)h) << 16; return v.f;
}

// flag: 0 = f32, 1 = fp16, 2 = bf16 storage of "float32" inputs
__device__ inline float ldin(const void* p, long i, int f) {
    if (f == 1) return __half2float(((const __half*)p)[i]);
    if (f == 2) return bf2f(((const unsigned short*)p)[i]);
    return ((const float*)p)[i];
}

// ---------------- dtype detector (no-op safety; R3 showed flag=0) ----------
// R6: wave-parallel. 64 lanes, coalesced strided loads, shfl reduction.
__global__ void detect_kernel(const void* w, int* flag) {
    const int lane = threadIdx.x;           // block of 64 = one wave
    const unsigned int* u32 = (const unsigned int*)w;
    const unsigned short* u16 = (const unsigned short*)w;
    int tiny = 0;
    for (int i = lane; i < 2048; i += 64) {
        unsigned int b = u32[i];
        float f; __builtin_memcpy(&f, &b, 4);
        float a = fabsf(f);
        if (!(a > 1e-10f)) tiny++;
    }
    int band = 0;
    for (int i = lane; i < 4096; i += 64) {
        unsigned short h = u16[i];
        int e8 = (h >> 7) & 0xFF;
        if (h == 0 || (e8 >= 0x66 && e8 <= 0x86)) band++;
    }
#pragma unroll
    for (int o = 32; o > 0; o >>= 1) {
        tiny += __shfl_down(tiny, o);
        band += __shfl_down(band, o);
    }
    if (lane == 0) {
        if (tiny > 1024) { *flag = 1; return; }
        *flag = (band > 3900) ? 2 : 0;
    }
}

// ---------------- canonicalize a float input to f32 (small buffers only) ----
__global__ void convert_kernel(const void* __restrict__ src, float* __restrict__ dst,
                               long n, const int* __restrict__ flag)
{
    int f = *flag;
    long stride = (long)gridDim.x * 256;
    for (long i = (long)blockIdx.x * 256 + threadIdx.x; i < n; i += stride)
        dst[i] = ldin(src, i, f);
}

// ---------------- token gather + mean over TPW ----------------
__global__ __launch_bounds__(256) void gather_mean_kernel(
    const void* __restrict__ tok, const int* __restrict__ widx,
    unsigned short* __restrict__ xb, const int* __restrict__ flag)
{
    int f = *flag;
    int n = blockIdx.x;
    long i0 = widx[n * 4 + 0], i1 = widx[n * 4 + 1];
    long i2 = widx[n * 4 + 2], i3 = widx[n * 4 + 3];
    for (int c = threadIdx.x; c < DIM; c += 256) {
        float s = ldin(tok, i0 * DIM + c, f) + ldin(tok, i1 * DIM + c, f)
                + ldin(tok, i2 * DIM + c, f) + ldin(tok, i3 * DIM + c, f);
        xb[(long)n * DIM + c] = f2bf(s * 0.25f);
    }
}

// ---------------- edge prep ----------------
__global__ void count_kernel(const int* __restrict__ ei, const int* __restrict__ et,
                             int* __restrict__ cnt)
{
    int e = blockIdx.x * 256 + threadIdx.x;
    if (e >= NEDGE) return;
    int dst = ei[NEDGE + e];
    int r = et[e];
    atomicAdd(&cnt[dst * RREL + r], 1);
}

// R7: thread-coarsened scan. 1024 threads x CH serial elements, one block
// scan over per-thread sums, second serial pass writes. ~22 barriers total
// (was ~800 barrier-rounds).
__global__ __launch_bounds__(1024) void scan_kernel(const int* __restrict__ cnt,
                                                    int* __restrict__ offs, int n)
{
    const int CH = (n + 1023) >> 10;        // 40 for n=40960
    int tid = threadIdx.x;
    int base = tid * CH;
    int s = 0;
    for (int i = 0; i < CH; i++)
        if (base + i < n) s += cnt[base + i];
    __shared__ int buf[1024];
    buf[tid] = s;
    __syncthreads();
    for (int o = 1; o < 1024; o <<= 1) {
        int t = (tid >= o) ? buf[tid - o] : 0;
        __syncthreads();
        buf[tid] += t;
        __syncthreads();
    }
    int run = (tid == 0) ? 0 : buf[tid - 1];   // exclusive prefix of this chunk
    if (tid == 0) offs[0] = 0;
    for (int i = 0; i < CH; i++) {
        if (base + i < n) {
            run += cnt[base + i];
            offs[base + i + 1] = run;
        }
    }
}

__global__ void fill_kernel(const int* __restrict__ ei, const int* __restrict__ et,
                            const int* __restrict__ offs, int* __restrict__ cursor,
                            int* __restrict__ sorted)
{
    int e = blockIdx.x * 256 + threadIdx.x;
    if (e >= NEDGE) return;
    int src = ei[e];
    int dst = ei[NEDGE + e];
    int r = et[e];
    int seg = dst * RREL + r;
    int pos = offs[seg] + atomicAdd(&cursor[seg], 1);
    sorted[pos] = src;
}

// ---------------- segment aggregation (per node) ----------------
__global__ __launch_bounds__(256) void aggregate_kernel(
    const unsigned short* __restrict__ xsrc, long xstride,
    const int* __restrict__ offs, const int* __restrict__ sorted,
    unsigned short* __restrict__ A, int write_root)
{
    int n = blockIdx.x;
    long base = (long)n * KBIG;
    for (int r = 0; r < RREL; r++) {
        int s0 = offs[n * RREL + r], s1 = offs[n * RREL + r + 1];
        float inv = 1.0f / (float)max(s1 - s0, 1);
        for (int c = threadIdx.x; c < DIM; c += 256) {
            float acc = 0.0f;
            for (int i = s0; i < s1; i++) {
                long s = sorted[i];
                acc += bf2f(xsrc[s * xstride + c]);
            }
            A[base + r * DIM + c] = f2bf(acc * inv);
        }
    }
    if (write_root) {
        for (int c = threadIdx.x; c < DIM; c += 256)
            A[base + 4 * DIM + c] = xsrc[(long)n * xstride + c];
    }
}

// ---------------- transpose + cast raw -> bf16 (R7: reads raw via ldin) ----
__global__ __launch_bounds__(256) void transpose_cast_kernel(
    const void* __restrict__ in, int Ncols,
    unsigned short* __restrict__ out, int outStride, int colOff,
    const int* __restrict__ flag)
{
    int f = *flag;
    __shared__ float t[32][33];
    int kt = blockIdx.x * 32, nt = blockIdx.y * 32;
    int lx = threadIdx.x & 31, ly = threadIdx.x >> 5;
    for (int i = 0; i < 4; i++)
        t[ly + i * 8][lx] = ldin(in, (long)(kt + ly + i * 8) * Ncols + nt + lx, f);
    __syncthreads();
    for (int i = 0; i < 4; i++)
        out[(long)(nt + ly + i * 8) * outStride + colOff + kt + lx] = f2bf(t[lx][ly + i * 8]);
}

// ---------------- MFMA GEMM: C = A (M,K) @ Bt^T, bf16 in, f32 acc --------
__global__ __launch_bounds__(256) void gemm_bt_kernel(
    const unsigned short* __restrict__ A, const unsigned short* __restrict__ Bt,
    int K, const float* __restrict__ bias, int relu,
    float* __restrict__ outF, long strideF,
    unsigned short* __restrict__ outB, long strideB)
{
    __shared__ __align__(16) unsigned short As[128 * 32];
    __shared__ __align__(16) unsigned short Bs[128 * 32];
    const int tid = threadIdx.x;
    const int lane = tid & 63, wv = tid >> 6;
    const int wr = wv >> 1, wc = wv & 1;
    const int lr = lane & 15, q = lane >> 4;
    const long m0 = (long)blockIdx.x * 128, n0 = (long)blockIdx.y * 128;

    f32x4 acc[4][4] = {};

    for (int kt = 0; kt < K; kt += 32) {
#pragma unroll
        for (int i = 0; i < 2; i++) {
            int chunk = i * 256 + tid;
            int row = chunk >> 2, kc = (chunk & 3) * 8;
            const unsigned short* ga = A + (m0 + row) * K + kt + kc;
            const unsigned short* gb = Bt + (n0 + row) * K + kt + kc;
            int ldsbase = (i * 256 + wv * 64) * 8;
            __builtin_amdgcn_global_load_lds(
                (const __attribute__((address_space(1))) void*)ga,
                (__attribute__((address_space(3))) void*)&As[ldsbase], 16, 0, 0);
            __builtin_amdgcn_global_load_lds(
                (const __attribute__((address_space(1))) void*)gb,
                (__attribute__((address_space(3))) void*)&Bs[ldsbase], 16, 0, 0);
        }
        __syncthreads();
        bf16x8 af[4], bfr[4];
#pragma unroll
        for (int i = 0; i < 4; i++)
            af[i] = *(const bf16x8*)&As[(wr * 64 + i * 16 + lr) * 32 + q * 8];
#pragma unroll
        for (int j = 0; j < 4; j++)
            bfr[j] = *(const bf16x8*)&Bs[(wc * 64 + j * 16 + lr) * 32 + q * 8];
#pragma unroll
        for (int i = 0; i < 4; i++)
#pragma unroll
            for (int j = 0; j < 4; j++)
                acc[i][j] = __builtin_amdgcn_mfma_f32_16x16x32_bf16(af[i], bfr[j], acc[i][j], 0, 0, 0);
        __syncthreads();
    }

#pragma unroll
    for (int i = 0; i < 4; i++) {
#pragma unroll
        for (int j = 0; j < 4; j++) {
            long col = n0 + wc * 64 + j * 16 + lr;
            float bv = bias ? bias[col] : 0.0f;
#pragma unroll
            for (int r = 0; r < 4; r++) {
                long row = m0 + wr * 64 + i * 16 + q * 4 + r;
                float v = acc[i][j][r] + bv;
                if (relu) v = fmaxf(v, 0.0f);
                if (outF) outF[row * strideF + col] = v;
                if (outB) outB[row * strideB + col] = f2bf(v);
            }
        }
    }
}

// ---------------- pooling (mean/max over words) + cc -> bf16 A3 + f32 evF ----
__global__ __launch_bounds__(256) void pool_cc_kernel(
    const float* __restrict__ C2, const void* __restrict__ tok,
    const int* __restrict__ csi, unsigned short* __restrict__ A3,
    float* __restrict__ evF, const int* __restrict__ flag)
{
    int f = *flag;
    int s = blockIdx.x;
    int b = s / EVI;
    long seq = csi[b];
    for (int c = threadIdx.x; c < DIM; c += 256) {
        float mx = -1e30f, sm = 0.0f;
        const float* col = C2 + (long)s * WORDS * DOUT + c;
        for (int w = 0; w < WORDS; w++) {
            float v = col[(long)w * DOUT];
            sm += v;
            mx = fmaxf(mx, v);
        }
        float mean = sm * (1.0f / WORDS);
        evF[(long)s * (2 * DOUT) + c] = mean;
        evF[(long)s * (2 * DOUT) + DOUT + c] = mx;
        A3[(long)s * KATT + c] = f2bf(ldin(tok, seq * LSEQ * DIM + c, f));
        A3[(long)s * KATT + DIM + c] = f2bf(mean);
        A3[(long)s * KATT + DIM + DOUT + c] = f2bf(mx);
    }
}

// ---------------- p = h @ att_w1 (R7: raw w1 via ldin) ----------------
__global__ __launch_bounds__(256) void pdot_kernel(
    const float* __restrict__ h, const void* __restrict__ w1, float* __restrict__ p,
    const int* __restrict__ flag)
{
    int f = *flag;
    int i = blockIdx.x;
    float s = 0.0f;
    for (int k = threadIdx.x; k < DOUT; k += 256) s += h[(long)i * DOUT + k] * ldin(w1, k, f);
    __shared__ float red[256];
    red[threadIdx.x] = s;
    __syncthreads();
    for (int o = 128; o > 0; o >>= 1) {
        if (threadIdx.x < o) red[threadIdx.x] += red[threadIdx.x + o];
        __syncthreads();
    }
    if (threadIdx.x == 0) p[i] = red[0];
}

// ---------------- attention output: sigmoid(p[i]) for all 320 rows ----------
__global__ void att_out_kernel(const float* __restrict__ p, float* __restrict__ out)
{
    int i = blockIdx.x * 256 + threadIdx.x;
    if (i < SEQS) out[BN * NCLS + i] = 1.0f / (1.0f + __expf(-p[i]));
}

// ---------------- softmax over EVI + weighted ev + build A4 (bf16) ----------
// R7: raw ccls via ldin.
__global__ __launch_bounds__(256) void softgraph_kernel(
    const float* __restrict__ p, const float* __restrict__ evF,
    const void* __restrict__ ccls, unsigned short* __restrict__ A4,
    const int* __restrict__ flag)
{
    int f = *flag;
    int b = blockIdx.x;
    __shared__ float a[EVI];
    if (threadIdx.x == 0) {
        float m = -1e30f;
        for (int e = 0; e < EVI; e++) m = fmaxf(m, p[b * EVI + e]);
        float s = 0.0f, ex[EVI];
        for (int e = 0; e < EVI; e++) { ex[e] = __expf(p[b * EVI + e] - m); s += ex[e]; }
        for (int e = 0; e < EVI; e++) a[e] = ex[e] / s;
    }
    __syncthreads();
    for (int d = threadIdx.x; d < 2 * DOUT; d += 256) {
        float g = 0.0f;
        for (int e = 0; e < EVI; e++)
            g += a[e] * evF[(long)(b * EVI + e) * (2 * DOUT) + d];
        A4[(long)b * KATT + d] = f2bf(g);
    }
    for (int c = threadIdx.x; c < DIM; c += 256)
        A4[(long)b * KATT + 2 * DOUT + c] = f2bf(ldin(ccls, (long)b * DIM + c, f));
}

// ---------------- final: lin2 + log_softmax (R7: raw w2/b2 via ldin) -------
__global__ __launch_bounds__(256) void final_kernel(
    const float* __restrict__ C4, const void* __restrict__ w2,
    const void* __restrict__ bb, float* __restrict__ out,
    const int* __restrict__ flag)
{
    int f = *flag;
    int b = blockIdx.x;
    float s0 = 0.0f, s1 = 0.0f, s2 = 0.0f;
    for (int k = threadIdx.x; k < LH; k += 256) {
        float h = C4[(long)b * LH + k];
        s0 += h * ldin(w2, k * NCLS + 0, f);
        s1 += h * ldin(w2, k * NCLS + 1, f);
        s2 += h * ldin(w2, k * NCLS + 2, f);
    }
    __shared__ float r0[256], r1[256], r2[256];
    int t = threadIdx.x;
    r0[t] = s0; r1[t] = s1; r2[t] = s2;
    __syncthreads();
    for (int o = 128; o > 0; o >>= 1) {
        if (t < o) { r0[t] += r0[t + o]; r1[t] += r1[t + o]; r2[t] += r2[t + o]; }
        __syncthreads();
    }
    if (t == 0) {
        float l0 = r0[0] + ldin(bb, 0, f), l1 = r1[0] + ldin(bb, 1, f), l2 = r2[0] + ldin(bb, 2, f);
        float m = fmaxf(l0, fmaxf(l1, l2));
        float lse = logf(__expf(l0 - m) + __expf(l1 - m) + __expf(l2 - m)) + m;
        out[b * NCLS + 0] = l0 - lse;
        out[b * NCLS + 1] = l1 - lse;
        out[b * NCLS + 2] = l2 - lse;
    }
}

extern "C" void kernel_launch(void* const* d_in, const int* in_sizes, int n_in,
                              void* d_out, int out_size, void* d_ws, size_t ws_size,
                              hipStream_t stream)
{
    const void* tok      = d_in[0];
    const void* ccls_r   = d_in[1];
    const void* W_rel1_r = d_in[2];
    const void* W_root1_r= d_in[3];
    const void* b1_r     = d_in[4];
    const void* W_rel2_r = d_in[5];
    const void* W_root2_r= d_in[6];
    const void* b2_r     = d_in[7];
    const void* att_w0_r = d_in[8];
    const void* att_w1_r = d_in[9];
    const void* lin1_w_r = d_in[10];
    const void* lin1_b_r = d_in[11];
    const void* lin2_w_r = d_in[12];
    const void* lin2_b_r = d_in[13];
    const int* widx      = (const int*)d_in[14];
    const int* ei        = (const int*)d_in[15];
    const int* et        = (const int*)d_in[16];
    const int* csi       = (const int*)d_in[17];
    float* out           = (float*)d_out;

    char* ws = (char*)d_ws;
    size_t off = 0;
    auto alloc = [&](size_t bytes) { size_t o = off; off = (off + bytes + 255) & ~(size_t)255; return o; };

    int* flag   = (int*)(ws + alloc(256));
    float* b1F     = (float*)(ws + alloc((size_t)DIM * 4));
    float* b2F     = (float*)(ws + alloc((size_t)DOUT * 4));
    float* l1bF    = (float*)(ws + alloc((size_t)LH * 4));
    unsigned short* xb  = (unsigned short*)(ws + alloc((size_t)NNODE * DIM * 2));
    unsigned short* A1  = (unsigned short*)(ws + alloc((size_t)NNODE * KBIG * 2));
    unsigned short* X1  = (unsigned short*)(ws + alloc((size_t)NNODE * DOUT * 2));
    unsigned short* Wt1 = (unsigned short*)(ws + alloc((size_t)DIM * KBIG * 2));
    unsigned short* Wt2 = (unsigned short*)(ws + alloc((size_t)DIM * KBIG * 2));
    unsigned short* Wt3 = (unsigned short*)(ws + alloc((size_t)DOUT * KATT * 2));
    unsigned short* Wt4 = (unsigned short*)(ws + alloc((size_t)LH * KATT * 2));
    float* C2           = (float*)(ws + alloc((size_t)NNODE * DOUT * 4));
    unsigned short* A3  = (unsigned short*)(ws + alloc((size_t)384 * KATT * 2));
    float* C3           = (float*)(ws + alloc((size_t)384 * DOUT * 4));
    float* evF          = (float*)(ws + alloc((size_t)SEQS * 2 * DOUT * 4));
    float* pbuf         = (float*)(ws + alloc((size_t)SEQS * 4));
    unsigned short* A4  = (unsigned short*)(ws + alloc((size_t)128 * KATT * 2));
    float* C4           = (float*)(ws + alloc((size_t)128 * LH * 4));
    int* cnt            = (int*)(ws + alloc((size_t)2 * NNODE * RREL * 4));
    int* cursor         = cnt + NNODE * RREL;
    int* offs           = (int*)(ws + alloc((size_t)(NNODE * RREL + 1) * 4));
    int* sorted         = (int*)(ws + alloc((size_t)NEDGE * 4));
    (void)ws_size; (void)in_sizes; (void)n_in; (void)out_size;

    // dtype detect + canonicalize small f32-typed consumers (gemm bias ptrs)
    detect_kernel<<<1, 64, 0, stream>>>(W_rel1_r, flag);
    auto conv = [&](const void* src, float* dst, long n) {
        int grid = (int)min((n + 255) / 256, (long)2048);
        convert_kernel<<<grid, 256, 0, stream>>>(src, dst, n, flag);
    };
    conv(b1_r,     b1F,     DIM);
    conv(b2_r,     b2F,     DOUT);
    conv(lin1_b_r, l1bF,    LH);

    // edge prep
    hipMemsetAsync(cnt, 0, (size_t)2 * NNODE * RREL * 4, stream);
    count_kernel<<<NEDGE / 256, 256, 0, stream>>>(ei, et, cnt);
    scan_kernel<<<1, 1024, 0, stream>>>(cnt, offs, NNODE * RREL);
    fill_kernel<<<NEDGE / 256, 256, 0, stream>>>(ei, et, offs, cursor, sorted);

    // token gather
    gather_mean_kernel<<<NNODE, 256, 0, stream>>>(tok, widx, xb, flag);

    // weight transposes (raw -> bf16, B^T layout) — R7: read raw via ldin
    transpose_cast_kernel<<<dim3(96, 24), 256, 0, stream>>>(W_rel1_r, DIM, Wt1, KBIG, 0, flag);
    transpose_cast_kernel<<<dim3(24, 24), 256, 0, stream>>>(W_root1_r, DIM, Wt1, KBIG, 4 * DIM, flag);
    transpose_cast_kernel<<<dim3(96, 24), 256, 0, stream>>>(W_rel2_r, DOUT, Wt2, KBIG, 0, flag);
    transpose_cast_kernel<<<dim3(24, 24), 256, 0, stream>>>(W_root2_r, DOUT, Wt2, KBIG, 4 * DIM, flag);
    transpose_cast_kernel<<<dim3(72, 24), 256, 0, stream>>>(att_w0_r, DOUT, Wt3, KATT, 0, flag);
    transpose_cast_kernel<<<dim3(72, 32), 256, 0, stream>>>(lin1_w_r, LH, Wt4, KATT, 0, flag);

    // layer 1: A1 = [agg_r(xb) | xb];  X1 = relu(A1 @ W1)
    aggregate_kernel<<<NNODE, 256, 0, stream>>>(xb, DIM, offs, sorted, A1, 1);
    gemm_bt_kernel<<<dim3(NNODE / 128, DIM / 128), 256, 0, stream>>>(
        A1, Wt1, KBIG, b1F, 1, nullptr, 0, X1, DOUT);

    // layer 2: A1 = [agg_r(X1) | X1];  C2 = relu(A1 @ W2)  (f32)
    aggregate_kernel<<<NNODE, 256, 0, stream>>>(X1, DOUT, offs, sorted, A1, 1);
    gemm_bt_kernel<<<dim3(NNODE / 128, DOUT / 128), 256, 0, stream>>>(
        A1, Wt2, KBIG, b2F, 1, C2, DOUT, nullptr, 0);

    // pooling + attention MLP (MFMA)
    pool_cc_kernel<<<SEQS, 256, 0, stream>>>(C2, tok, csi, A3, evF, flag);
    gemm_bt_kernel<<<dim3(3, DOUT / 128), 256, 0, stream>>>(
        A3, Wt3, KATT, nullptr, 1, C3, DOUT, nullptr, 0);
    pdot_kernel<<<SEQS, 256, 0, stream>>>(C3, att_w1_r, pbuf, flag);
    att_out_kernel<<<(SEQS + 255) / 256, 256, 0, stream>>>(pbuf, out);
    softgraph_kernel<<<BN, 256, 0, stream>>>(pbuf, evF, ccls_r, A4, flag);

    // classifier head (MFMA)
    gemm_bt_kernel<<<dim3(1, LH / 128), 256, 0, stream>>>(
        A4, Wt4, KATT, l1bF, 1, C4, LH, nullptr, 0);
    final_kernel<<<BN, 256, 0, stream>>>(C4, lin2_w_r, lin2_b_r, out, flag);
}

// Round 4
// 955.519 us; speedup vs baseline: 1.2771x; 1.1076x over previous
//
#include <hip/hip_runtime.h>
#include <hip/hip_fp16.h>

// Journal:
// R1: full pipeline, MFMA everywhere -> out0 err 0.59; out1 structurally wrong.
// R2: out1 fixed; post-pool all-f32 -> err bit-identical 0.59375.
// R3: dtype-detector theory -> flag=0 (f32 inputs), no change. Wrong theory.
// R4: REAL BUG: log_softmax subtracted m twice. PASSED, absmax 0.0078,
//     dur 6543us. Profile: sgemm_simple 2x3030us = latency-bound serial GEMM.
// R5: att-MLP + lin1 back on MFMA gemm_bt: 6543 -> 1220us.
// R6: wave-parallel detect (was 1 lane, 181us serial): 1220 -> 1072us. Matched.
// R7: killed 10/13 converts + coarsened scan: 1072 -> 1058 (-14 vs -60..100
//     predicted). MISS: converts/scan were cheap; budget model wrong.
// R8: budget re-derivation: all our kernels <148us (fillBuffer masks top-5);
//     gemms ~110 each, tail ~190 => ~300-400us unexplained = the 2 aggregates
//     (fits <=148 bound). Inner loop was chain-serialized: sorted[i] load ->
//     dependent row gather, x3 col-chunk passes re-walking edges. Fix:
//     LDS-stage edge list once, 384thr x dword (1 pass), edge loop unrolled
//     x4 with independent partials (4 gathers in flight).
//     Predict aggregate ~130 -> ~40us each; total 1058 -> ~850.
// R9: R8 bench died with "MI355X container failed twice" = infra flake, zero
//     signal. Audit found no crash mechanism (eidx guarded, aligned dword
//     access, uniform barriers). Resubmitting R8 unchanged; same prediction.

#define BN 64
#define EVI 5
#define SEQS (BN * EVI)
#define LSEQ 256
#define DIM 768
#define WORDS 32
#define TPW 4
#define NNODE (BN * EVI * WORDS)   // 10240
#define NEDGE (NNODE * 16)         // 163840
#define RREL 4
#define DOUT 768
#define LH 1024
#define NCLS 3
#define KBIG (5 * DIM)             // 3840
#define KATT (DIM + 2 * DOUT)      // 2304

typedef float f32x4 __attribute__((ext_vector_type(4)));
typedef __bf16 bf16x8 __attribute__((ext_vector_type(8)));

__device__ inline unsigned short f2bf(float f) {
    union { float f; unsigned int u; } v; v.f = f;
    unsigned int u = v.u;
    unsigned int lsb = (u >> 16) & 1u;
    u += 0x7fffu + lsb;
    return (unsigned short)(u >> 16);
}
__device__ inline float bf2f(unsigned short h) {
    union { float f; unsigned int u; } v; v.u = ((unsigned int)h) << 16; return v.f;
}

// flag: 0 = f32, 1 = fp16, 2 = bf16 storage of "float32" inputs
__device__ inline float ldin(const void* p, long i, int f) {
    if (f == 1) return __half2float(((const __half*)p)[i]);
    if (f == 2) return bf2f(((const unsigned short*)p)[i]);
    return ((const float*)p)[i];
}

// ---------------- dtype detector (no-op safety; R3 showed flag=0) ----------
__global__ void detect_kernel(const void* w, int* flag) {
    const int lane = threadIdx.x;           // block of 64 = one wave
    const unsigned int* u32 = (const unsigned int*)w;
    const unsigned short* u16 = (const unsigned short*)w;
    int tiny = 0;
    for (int i = lane; i < 2048; i += 64) {
        unsigned int b = u32[i];
        float f; __builtin_memcpy(&f, &b, 4);
        float a = fabsf(f);
        if (!(a > 1e-10f)) tiny++;
    }
    int band = 0;
    for (int i = lane; i < 4096; i += 64) {
        unsigned short h = u16[i];
        int e8 = (h >> 7) & 0xFF;
        if (h == 0 || (e8 >= 0x66 && e8 <= 0x86)) band++;
    }
#pragma unroll
    for (int o = 32; o > 0; o >>= 1) {
        tiny += __shfl_down(tiny, o);
        band += __shfl_down(band, o);
    }
    if (lane == 0) {
        if (tiny > 1024) { *flag = 1; return; }
        *flag = (band > 3900) ? 2 : 0;
    }
}

// ---------------- canonicalize a float input to f32 (small buffers only) ----
__global__ void convert_kernel(const void* __restrict__ src, float* __restrict__ dst,
                               long n, const int* __restrict__ flag)
{
    int f = *flag;
    long stride = (long)gridDim.x * 256;
    for (long i = (long)blockIdx.x * 256 + threadIdx.x; i < n; i += stride)
        dst[i] = ldin(src, i, f);
}

// ---------------- token gather + mean over TPW ----------------
__global__ __launch_bounds__(256) void gather_mean_kernel(
    const void* __restrict__ tok, const int* __restrict__ widx,
    unsigned short* __restrict__ xb, const int* __restrict__ flag)
{
    int f = *flag;
    int n = blockIdx.x;
    long i0 = widx[n * 4 + 0], i1 = widx[n * 4 + 1];
    long i2 = widx[n * 4 + 2], i3 = widx[n * 4 + 3];
    for (int c = threadIdx.x; c < DIM; c += 256) {
        float s = ldin(tok, i0 * DIM + c, f) + ldin(tok, i1 * DIM + c, f)
                + ldin(tok, i2 * DIM + c, f) + ldin(tok, i3 * DIM + c, f);
        xb[(long)n * DIM + c] = f2bf(s * 0.25f);
    }
}

// ---------------- edge prep ----------------
__global__ void count_kernel(const int* __restrict__ ei, const int* __restrict__ et,
                             int* __restrict__ cnt)
{
    int e = blockIdx.x * 256 + threadIdx.x;
    if (e >= NEDGE) return;
    int dst = ei[NEDGE + e];
    int r = et[e];
    atomicAdd(&cnt[dst * RREL + r], 1);
}

// R7: thread-coarsened scan, ~22 barriers.
__global__ __launch_bounds__(1024) void scan_kernel(const int* __restrict__ cnt,
                                                    int* __restrict__ offs, int n)
{
    const int CH = (n + 1023) >> 10;        // 40 for n=40960
    int tid = threadIdx.x;
    int base = tid * CH;
    int s = 0;
    for (int i = 0; i < CH; i++)
        if (base + i < n) s += cnt[base + i];
    __shared__ int buf[1024];
    buf[tid] = s;
    __syncthreads();
    for (int o = 1; o < 1024; o <<= 1) {
        int t = (tid >= o) ? buf[tid - o] : 0;
        __syncthreads();
        buf[tid] += t;
        __syncthreads();
    }
    int run = (tid == 0) ? 0 : buf[tid - 1];   // exclusive prefix of this chunk
    if (tid == 0) offs[0] = 0;
    for (int i = 0; i < CH; i++) {
        if (base + i < n) {
            run += cnt[base + i];
            offs[base + i + 1] = run;
        }
    }
}

__global__ void fill_kernel(const int* __restrict__ ei, const int* __restrict__ et,
                            const int* __restrict__ offs, int* __restrict__ cursor,
                            int* __restrict__ sorted)
{
    int e = blockIdx.x * 256 + threadIdx.x;
    if (e >= NEDGE) return;
    int src = ei[e];
    int dst = ei[NEDGE + e];
    int r = et[e];
    int seg = dst * RREL + r;
    int pos = offs[seg] + atomicAdd(&cursor[seg], 1);
    sorted[pos] = src;
}

// ---------------- segment aggregation (per node) ----------------
// R8: LDS-staged edge list (one pass), 384 thr x dword, edge loop unrolled x4
// with 4 independent partial accumulators (4 gathers in flight).
__global__ __launch_bounds__(384) void aggregate_kernel(
    const unsigned short* __restrict__ xsrc, long xstride,
    const int* __restrict__ offs, const int* __restrict__ sorted,
    unsigned short* __restrict__ A, int write_root)
{
    const int n = blockIdx.x;
    const int t = threadIdx.x;                 // dword index within row (384 = DIM/2)
    const long base = (long)n * KBIG;
    const int o0 = offs[n * RREL + 0];
    const int o1 = offs[n * RREL + 1];
    const int o2 = offs[n * RREL + 2];
    const int o3 = offs[n * RREL + 3];
    const int o4 = offs[n * RREL + 4];
    const int tot = o4 - o0;
    __shared__ int eidx[128];
    for (int i = t; i < tot && i < 128; i += 384) eidx[i] = sorted[o0 + i];
    __syncthreads();
    const unsigned int* xs32 = (const unsigned int*)xsrc;
    const long rsd = xstride >> 1;             // row stride in dwords
    unsigned int* A32 = (unsigned int*)A;
    const long baseD = base >> 1;
    const int rb0 = 0, rb1 = o1 - o0, rb2 = o2 - o0, rb3 = o3 - o0, rb4 = o4 - o0;
#pragma unroll
    for (int r = 0; r < RREL; r++) {
        const int s0 = (r == 0) ? rb0 : (r == 1) ? rb1 : (r == 2) ? rb2 : rb3;
        const int s1 = (r == 0) ? rb1 : (r == 1) ? rb2 : (r == 2) ? rb3 : rb4;
        float inv = 1.0f / (float)max(s1 - s0, 1);
        float x0 = 0, x1 = 0, x2 = 0, x3 = 0;
        float y0 = 0, y1 = 0, y2 = 0, y3 = 0;
        int i = s0;
        for (; i + 3 < s1; i += 4) {
            int p0 = (i     < 128) ? eidx[i]     : sorted[o0 + i];
            int p1 = (i + 1 < 128) ? eidx[i + 1] : sorted[o0 + i + 1];
            int p2 = (i + 2 < 128) ? eidx[i + 2] : sorted[o0 + i + 2];
            int p3 = (i + 3 < 128) ? eidx[i + 3] : sorted[o0 + i + 3];
            unsigned int w0 = xs32[(long)p0 * rsd + t];
            unsigned int w1 = xs32[(long)p1 * rsd + t];
            unsigned int w2 = xs32[(long)p2 * rsd + t];
            unsigned int w3 = xs32[(long)p3 * rsd + t];
            x0 += bf2f((unsigned short)(w0 & 0xffff)); y0 += bf2f((unsigned short)(w0 >> 16));
            x1 += bf2f((unsigned short)(w1 & 0xffff)); y1 += bf2f((unsigned short)(w1 >> 16));
            x2 += bf2f((unsigned short)(w2 & 0xffff)); y2 += bf2f((unsigned short)(w2 >> 16));
            x3 += bf2f((unsigned short)(w3 & 0xffff)); y3 += bf2f((unsigned short)(w3 >> 16));
        }
        for (; i < s1; i++) {
            int p = (i < 128) ? eidx[i] : sorted[o0 + i];
            unsigned int w = xs32[(long)p * rsd + t];
            x0 += bf2f((unsigned short)(w & 0xffff)); y0 += bf2f((unsigned short)(w >> 16));
        }
        float xs = (x0 + x1) + (x2 + x3);
        float ys = (y0 + y1) + (y2 + y3);
        unsigned int pack = (unsigned int)f2bf(xs * inv) | ((unsigned int)f2bf(ys * inv) << 16);
        A32[baseD + ((r * DIM) >> 1) + t] = pack;
    }
    if (write_root)
        A32[baseD + ((4 * DIM) >> 1) + t] = xs32[(long)n * rsd + t];
}

// ---------------- transpose + cast raw -> bf16 (reads raw via ldin) ----
__global__ __launch_bounds__(256) void transpose_cast_kernel(
    const void* __restrict__ in, int Ncols,
    unsigned short* __restrict__ out, int outStride, int colOff,
    const int* __restrict__ flag)
{
    int f = *flag;
    __shared__ float t[32][33];
    int kt = blockIdx.x * 32, nt = blockIdx.y * 32;
    int lx = threadIdx.x & 31, ly = threadIdx.x >> 5;
    for (int i = 0; i < 4; i++)
        t[ly + i * 8][lx] = ldin(in, (long)(kt + ly + i * 8) * Ncols + nt + lx, f);
    __syncthreads();
    for (int i = 0; i < 4; i++)
        out[(long)(nt + ly + i * 8) * outStride + colOff + kt + lx] = f2bf(t[lx][ly + i * 8]);
}

// ---------------- MFMA GEMM: C = A (M,K) @ Bt^T, bf16 in, f32 acc --------
__global__ __launch_bounds__(256) void gemm_bt_kernel(
    const unsigned short* __restrict__ A, const unsigned short* __restrict__ Bt,
    int K, const float* __restrict__ bias, int relu,
    float* __restrict__ outF, long strideF,
    unsigned short* __restrict__ outB, long strideB)
{
    __shared__ __align__(16) unsigned short As[128 * 32];
    __shared__ __align__(16) unsigned short Bs[128 * 32];
    const int tid = threadIdx.x;
    const int lane = tid & 63, wv = tid >> 6;
    const int wr = wv >> 1, wc = wv & 1;
    const int lr = lane & 15, q = lane >> 4;
    const long m0 = (long)blockIdx.x * 128, n0 = (long)blockIdx.y * 128;

    f32x4 acc[4][4] = {};

    for (int kt = 0; kt < K; kt += 32) {
#pragma unroll
        for (int i = 0; i < 2; i++) {
            int chunk = i * 256 + tid;
            int row = chunk >> 2, kc = (chunk & 3) * 8;
            const unsigned short* ga = A + (m0 + row) * K + kt + kc;
            const unsigned short* gb = Bt + (n0 + row) * K + kt + kc;
            int ldsbase = (i * 256 + wv * 64) * 8;
            __builtin_amdgcn_global_load_lds(
                (const __attribute__((address_space(1))) void*)ga,
                (__attribute__((address_space(3))) void*)&As[ldsbase], 16, 0, 0);
            __builtin_amdgcn_global_load_lds(
                (const __attribute__((address_space(1))) void*)gb,
                (__attribute__((address_space(3))) void*)&Bs[ldsbase], 16, 0, 0);
        }
        __syncthreads();
        bf16x8 af[4], bfr[4];
#pragma unroll
        for (int i = 0; i < 4; i++)
            af[i] = *(const bf16x8*)&As[(wr * 64 + i * 16 + lr) * 32 + q * 8];
#pragma unroll
        for (int j = 0; j < 4; j++)
            bfr[j] = *(const bf16x8*)&Bs[(wc * 64 + j * 16 + lr) * 32 + q * 8];
#pragma unroll
        for (int i = 0; i < 4; i++)
#pragma unroll
            for (int j = 0; j < 4; j++)
                acc[i][j] = __builtin_amdgcn_mfma_f32_16x16x32_bf16(af[i], bfr[j], acc[i][j], 0, 0, 0);
        __syncthreads();
    }

#pragma unroll
    for (int i = 0; i < 4; i++) {
#pragma unroll
        for (int j = 0; j < 4; j++) {
            long col = n0 + wc * 64 + j * 16 + lr;
            float bv = bias ? bias[col] : 0.0f;
#pragma unroll
            for (int r = 0; r < 4; r++) {
                long row = m0 + wr * 64 + i * 16 + q * 4 + r;
                float v = acc[i][j][r] + bv;
                if (relu) v = fmaxf(v, 0.0f);
                if (outF) outF[row * strideF + col] = v;
                if (outB) outB[row * strideB + col] = f2bf(v);
            }
        }
    }
}

// ---------------- pooling (mean/max over words) + cc -> bf16 A3 + f32 evF ----
__global__ __launch_bounds__(256) void pool_cc_kernel(
    const float* __restrict__ C2, const void* __restrict__ tok,
    const int* __restrict__ csi, unsigned short* __restrict__ A3,
    float* __restrict__ evF, const int* __restrict__ flag)
{
    int f = *flag;
    int s = blockIdx.x;
    int b = s / EVI;
    long seq = csi[b];
    for (int c = threadIdx.x; c < DIM; c += 256) {
        float mx = -1e30f, sm = 0.0f;
        const float* col = C2 + (long)s * WORDS * DOUT + c;
        for (int w = 0; w < WORDS; w++) {
            float v = col[(long)w * DOUT];
            sm += v;
            mx = fmaxf(mx, v);
        }
        float mean = sm * (1.0f / WORDS);
        evF[(long)s * (2 * DOUT) + c] = mean;
        evF[(long)s * (2 * DOUT) + DOUT + c] = mx;
        A3[(long)s * KATT + c] = f2bf(ldin(tok, seq * LSEQ * DIM + c, f));
        A3[(long)s * KATT + DIM + c] = f2bf(mean);
        A3[(long)s * KATT + DIM + DOUT + c] = f2bf(mx);
    }
}

// ---------------- p = h @ att_w1 (raw w1 via ldin) ----------------
__global__ __launch_bounds__(256) void pdot_kernel(
    const float* __restrict__ h, const void* __restrict__ w1, float* __restrict__ p,
    const int* __restrict__ flag)
{
    int f = *flag;
    int i = blockIdx.x;
    float s = 0.0f;
    for (int k = threadIdx.x; k < DOUT; k += 256) s += h[(long)i * DOUT + k] * ldin(w1, k, f);
    __shared__ float red[256];
    red[threadIdx.x] = s;
    __syncthreads();
    for (int o = 128; o > 0; o >>= 1) {
        if (threadIdx.x < o) red[threadIdx.x] += red[threadIdx.x + o];
        __syncthreads();
    }
    if (threadIdx.x == 0) p[i] = red[0];
}

// ---------------- attention output: sigmoid(p[i]) for all 320 rows ----------
__global__ void att_out_kernel(const float* __restrict__ p, float* __restrict__ out)
{
    int i = blockIdx.x * 256 + threadIdx.x;
    if (i < SEQS) out[BN * NCLS + i] = 1.0f / (1.0f + __expf(-p[i]));
}

// ---------------- softmax over EVI + weighted ev + build A4 (bf16) ----------
__global__ __launch_bounds__(256) void softgraph_kernel(
    const float* __restrict__ p, const float* __restrict__ evF,
    const void* __restrict__ ccls, unsigned short* __restrict__ A4,
    const int* __restrict__ flag)
{
    int f = *flag;
    int b = blockIdx.x;
    __shared__ float a[EVI];
    if (threadIdx.x == 0) {
        float m = -1e30f;
        for (int e = 0; e < EVI; e++) m = fmaxf(m, p[b * EVI + e]);
        float s = 0.0f, ex[EVI];
        for (int e = 0; e < EVI; e++) { ex[e] = __expf(p[b * EVI + e] - m); s += ex[e]; }
        for (int e = 0; e < EVI; e++) a[e] = ex[e] / s;
    }
    __syncthreads();
    for (int d = threadIdx.x; d < 2 * DOUT; d += 256) {
        float g = 0.0f;
        for (int e = 0; e < EVI; e++)
            g += a[e] * evF[(long)(b * EVI + e) * (2 * DOUT) + d];
        A4[(long)b * KATT + d] = f2bf(g);
    }
    for (int c = threadIdx.x; c < DIM; c += 256)
        A4[(long)b * KATT + 2 * DOUT + c] = f2bf(ldin(ccls, (long)b * DIM + c, f));
}

// ---------------- final: lin2 + log_softmax (raw w2/b2 via ldin) -------
__global__ __launch_bounds__(256) void final_kernel(
    const float* __restrict__ C4, const void* __restrict__ w2,
    const void* __restrict__ bb, float* __restrict__ out,
    const int* __restrict__ flag)
{
    int f = *flag;
    int b = blockIdx.x;
    float s0 = 0.0f, s1 = 0.0f, s2 = 0.0f;
    for (int k = threadIdx.x; k < LH; k += 256) {
        float h = C4[(long)b * LH + k];
        s0 += h * ldin(w2, k * NCLS + 0, f);
        s1 += h * ldin(w2, k * NCLS + 1, f);
        s2 += h * ldin(w2, k * NCLS + 2, f);
    }
    __shared__ float r0[256], r1[256], r2[256];
    int t = threadIdx.x;
    r0[t] = s0; r1[t] = s1; r2[t] = s2;
    __syncthreads();
    for (int o = 128; o > 0; o >>= 1) {
        if (t < o) { r0[t] += r0[t + o]; r1[t] += r1[t + o]; r2[t] += r2[t + o]; }
        __syncthreads();
    }
    if (t == 0) {
        float l0 = r0[0] + ldin(bb, 0, f), l1 = r1[0] + ldin(bb, 1, f), l2 = r2[0] + ldin(bb, 2, f);
        float m = fmaxf(l0, fmaxf(l1, l2));
        float lse = logf(__expf(l0 - m) + __expf(l1 - m) + __expf(l2 - m)) + m;
        out[b * NCLS + 0] = l0 - lse;
        out[b * NCLS + 1] = l1 - lse;
        out[b * NCLS + 2] = l2 - lse;
    }
}

extern "C" void kernel_launch(void* const* d_in, const int* in_sizes, int n_in,
                              void* d_out, int out_size, void* d_ws, size_t ws_size,
                              hipStream_t stream)
{
    const void* tok      = d_in[0];
    const void* ccls_r   = d_in[1];
    const void* W_rel1_r = d_in[2];
    const void* W_root1_r= d_in[3];
    const void* b1_r     = d_in[4];
    const void* W_rel2_r = d_in[5];
    const void* W_root2_r= d_in[6];
    const void* b2_r     = d_in[7];
    const void* att_w0_r = d_in[8];
    const void* att_w1_r = d_in[9];
    const void* lin1_w_r = d_in[10];
    const void* lin1_b_r = d_in[11];
    const void* lin2_w_r = d_in[12];
    const void* lin2_b_r = d_in[13];
    const int* widx      = (const int*)d_in[14];
    const int* ei        = (const int*)d_in[15];
    const int* et        = (const int*)d_in[16];
    const int* csi       = (const int*)d_in[17];
    float* out           = (float*)d_out;

    char* ws = (char*)d_ws;
    size_t off = 0;
    auto alloc = [&](size_t bytes) { size_t o = off; off = (off + bytes + 255) & ~(size_t)255; return o; };

    int* flag   = (int*)(ws + alloc(256));
    float* b1F     = (float*)(ws + alloc((size_t)DIM * 4));
    float* b2F     = (float*)(ws + alloc((size_t)DOUT * 4));
    float* l1bF    = (float*)(ws + alloc((size_t)LH * 4));
    unsigned short* xb  = (unsigned short*)(ws + alloc((size_t)NNODE * DIM * 2));
    unsigned short* A1  = (unsigned short*)(ws + alloc((size_t)NNODE * KBIG * 2));
    unsigned short* X1  = (unsigned short*)(ws + alloc((size_t)NNODE * DOUT * 2));
    unsigned short* Wt1 = (unsigned short*)(ws + alloc((size_t)DIM * KBIG * 2));
    unsigned short* Wt2 = (unsigned short*)(ws + alloc((size_t)DIM * KBIG * 2));
    unsigned short* Wt3 = (unsigned short*)(ws + alloc((size_t)DOUT * KATT * 2));
    unsigned short* Wt4 = (unsigned short*)(ws + alloc((size_t)LH * KATT * 2));
    float* C2           = (float*)(ws + alloc((size_t)NNODE * DOUT * 4));
    unsigned short* A3  = (unsigned short*)(ws + alloc((size_t)384 * KATT * 2));
    float* C3           = (float*)(ws + alloc((size_t)384 * DOUT * 4));
    float* evF          = (float*)(ws + alloc((size_t)SEQS * 2 * DOUT * 4));
    float* pbuf         = (float*)(ws + alloc((size_t)SEQS * 4));
    unsigned short* A4  = (unsigned short*)(ws + alloc((size_t)128 * KATT * 2));
    float* C4           = (float*)(ws + alloc((size_t)128 * LH * 4));
    int* cnt            = (int*)(ws + alloc((size_t)2 * NNODE * RREL * 4));
    int* cursor         = cnt + NNODE * RREL;
    int* offs           = (int*)(ws + alloc((size_t)(NNODE * RREL + 1) * 4));
    int* sorted         = (int*)(ws + alloc((size_t)NEDGE * 4));
    (void)ws_size; (void)in_sizes; (void)n_in; (void)out_size;

    // dtype detect + canonicalize small f32-typed consumers (gemm bias ptrs)
    detect_kernel<<<1, 64, 0, stream>>>(W_rel1_r, flag);
    auto conv = [&](const void* src, float* dst, long n) {
        int grid = (int)min((n + 255) / 256, (long)2048);
        convert_kernel<<<grid, 256, 0, stream>>>(src, dst, n, flag);
    };
    conv(b1_r,     b1F,     DIM);
    conv(b2_r,     b2F,     DOUT);
    conv(lin1_b_r, l1bF,    LH);

    // edge prep
    hipMemsetAsync(cnt, 0, (size_t)2 * NNODE * RREL * 4, stream);
    count_kernel<<<NEDGE / 256, 256, 0, stream>>>(ei, et, cnt);
    scan_kernel<<<1, 1024, 0, stream>>>(cnt, offs, NNODE * RREL);
    fill_kernel<<<NEDGE / 256, 256, 0, stream>>>(ei, et, offs, cursor, sorted);

    // token gather
    gather_mean_kernel<<<NNODE, 256, 0, stream>>>(tok, widx, xb, flag);

    // weight transposes (raw -> bf16, B^T layout)
    transpose_cast_kernel<<<dim3(96, 24), 256, 0, stream>>>(W_rel1_r, DIM, Wt1, KBIG, 0, flag);
    transpose_cast_kernel<<<dim3(24, 24), 256, 0, stream>>>(W_root1_r, DIM, Wt1, KBIG, 4 * DIM, flag);
    transpose_cast_kernel<<<dim3(96, 24), 256, 0, stream>>>(W_rel2_r, DOUT, Wt2, KBIG, 0, flag);
    transpose_cast_kernel<<<dim3(24, 24), 256, 0, stream>>>(W_root2_r, DOUT, Wt2, KBIG, 4 * DIM, flag);
    transpose_cast_kernel<<<dim3(72, 24), 256, 0, stream>>>(att_w0_r, DOUT, Wt3, KATT, 0, flag);
    transpose_cast_kernel<<<dim3(72, 32), 256, 0, stream>>>(lin1_w_r, LH, Wt4, KATT, 0, flag);

    // layer 1: A1 = [agg_r(xb) | xb];  X1 = relu(A1 @ W1)
    aggregate_kernel<<<NNODE, 384, 0, stream>>>(xb, DIM, offs, sorted, A1, 1);
    gemm_bt_kernel<<<dim3(NNODE / 128, DIM / 128), 256, 0, stream>>>(
        A1, Wt1, KBIG, b1F, 1, nullptr, 0, X1, DOUT);

    // layer 2: A1 = [agg_r(X1) | X1];  C2 = relu(A1 @ W2)  (f32)
    aggregate_kernel<<<NNODE, 384, 0, stream>>>(X1, DOUT, offs, sorted, A1, 1);
    gemm_bt_kernel<<<dim3(NNODE / 128, DOUT / 128), 256, 0, stream>>>(
        A1, Wt2, KBIG, b2F, 1, C2, DOUT, nullptr, 0);

    // pooling + attention MLP (MFMA)
    pool_cc_kernel<<<SEQS, 256, 0, stream>>>(C2, tok, csi, A3, evF, flag);
    gemm_bt_kernel<<<dim3(3, DOUT / 128), 256, 0, stream>>>(
        A3, Wt3, KATT, nullptr, 1, C3, DOUT, nullptr, 0);
    pdot_kernel<<<SEQS, 256, 0, stream>>>(C3, att_w1_r, pbuf, flag);
    att_out_kernel<<<(SEQS + 255) / 256, 256, 0, stream>>>(pbuf, out);
    softgraph_kernel<<<BN, 256, 0, stream>>>(pbuf, evF, ccls_r, A4, flag);

    // classifier head (MFMA)
    gemm_bt_kernel<<<dim3(1, LH / 128), 256, 0, stream>>>(
        A4, Wt4, KATT, l1bF, 1, C4, LH, nullptr, 0);
    final_kernel<<<BN, 256, 0, stream>>>(C4, lin2_w_r, lin2_b_r, out, flag);
}

// Round 5
// 949.962 us; speedup vs baseline: 1.2846x; 1.0059x over previous
//
#include <hip/hip_runtime.h>
#include <hip/hip_fp16.h>

// Journal:
// R1: full pipeline, MFMA everywhere -> out0 err 0.59; out1 structurally wrong.
// R2: out1 fixed; post-pool all-f32 -> err bit-identical 0.59375.
// R3: dtype-detector theory -> flag=0 (f32 inputs), no change. Wrong theory.
// R4: REAL BUG: log_softmax subtracted m twice. PASSED, absmax 0.0078,
//     dur 6543us. Profile: sgemm_simple 2x3030us = latency-bound serial GEMM.
// R5: att-MLP + lin1 back on MFMA gemm_bt: 6543 -> 1220us.
// R6: wave-parallel detect (was 1 lane, 181us serial): 1220 -> 1072us. Matched.
// R7: killed 10/13 converts + coarsened scan: 1072 -> 1058 (-14 vs -60..100
//     predicted). MISS: converts/scan were cheap; budget model wrong.
// R8: aggregate rewrite v1 (LDS edge list, 1 pass, x4 unroll).
// R9: infra flake, resubmitted. 1058 -> 955 (-103 vs -150..250 predicted).
//     Mechanism confirmed (latency-bound aggregate); still ~95us each vs
//     ~50us L3-BW floor (252MB L3 reads + 79MB writes per aggregate).
// R10: aggregate v2: 768 thr = 4 groups x 192 lanes (3 waves, no intra-wave
//     divergence); group g owns relation g (kills serial r-loop); ushort4
//     (8B) loads; x4 neighbor unroll -> 16 loads in flight. Also merged
//     pdot+att_out+softgraph into att_finish (one 64-block kernel, -2
//     launches). GEMMs untouched. Predict aggregates 2x95 -> 2x50, tail -10;
//     total 955 -> ~850. absmax unchanged.

#define BN 64
#define EVI 5
#define SEQS (BN * EVI)
#define LSEQ 256
#define DIM 768
#define WORDS 32
#define TPW 4
#define NNODE (BN * EVI * WORDS)   // 10240
#define NEDGE (NNODE * 16)         // 163840
#define RREL 4
#define DOUT 768
#define LH 1024
#define NCLS 3
#define KBIG (5 * DIM)             // 3840
#define KATT (DIM + 2 * DOUT)      // 2304

typedef float f32x4 __attribute__((ext_vector_type(4)));
typedef __bf16 bf16x8 __attribute__((ext_vector_type(8)));
typedef unsigned short u16x4 __attribute__((ext_vector_type(4)));

__device__ inline unsigned short f2bf(float f) {
    union { float f; unsigned int u; } v; v.f = f;
    unsigned int u = v.u;
    unsigned int lsb = (u >> 16) & 1u;
    u += 0x7fffu + lsb;
    return (unsigned short)(u >> 16);
}
__device__ inline float bf2f(unsigned short h) {
    union { float f; unsigned int u; } v; v.u = ((unsigned int)h) << 16; return v.f;
}

// flag: 0 = f32, 1 = fp16, 2 = bf16 storage of "float32" inputs
__device__ inline float ldin(const void* p, long i, int f) {
    if (f == 1) return __half2float(((const __half*)p)[i]);
    if (f == 2) return bf2f(((const unsigned short*)p)[i]);
    return ((const float*)p)[i];
}

// ---------------- dtype detector (no-op safety; R3 showed flag=0) ----------
__global__ void detect_kernel(const void* w, int* flag) {
    const int lane = threadIdx.x;           // block of 64 = one wave
    const unsigned int* u32 = (const unsigned int*)w;
    const unsigned short* u16 = (const unsigned short*)w;
    int tiny = 0;
    for (int i = lane; i < 2048; i += 64) {
        unsigned int b = u32[i];
        float f; __builtin_memcpy(&f, &b, 4);
        float a = fabsf(f);
        if (!(a > 1e-10f)) tiny++;
    }
    int band = 0;
    for (int i = lane; i < 4096; i += 64) {
        unsigned short h = u16[i];
        int e8 = (h >> 7) & 0xFF;
        if (h == 0 || (e8 >= 0x66 && e8 <= 0x86)) band++;
    }
#pragma unroll
    for (int o = 32; o > 0; o >>= 1) {
        tiny += __shfl_down(tiny, o);
        band += __shfl_down(band, o);
    }
    if (lane == 0) {
        if (tiny > 1024) { *flag = 1; return; }
        *flag = (band > 3900) ? 2 : 0;
    }
}

// ---------------- canonicalize a float input to f32 (small buffers only) ----
__global__ void convert_kernel(const void* __restrict__ src, float* __restrict__ dst,
                               long n, const int* __restrict__ flag)
{
    int f = *flag;
    long stride = (long)gridDim.x * 256;
    for (long i = (long)blockIdx.x * 256 + threadIdx.x; i < n; i += stride)
        dst[i] = ldin(src, i, f);
}

// ---------------- token gather + mean over TPW ----------------
__global__ __launch_bounds__(256) void gather_mean_kernel(
    const void* __restrict__ tok, const int* __restrict__ widx,
    unsigned short* __restrict__ xb, const int* __restrict__ flag)
{
    int f = *flag;
    int n = blockIdx.x;
    long i0 = widx[n * 4 + 0], i1 = widx[n * 4 + 1];
    long i2 = widx[n * 4 + 2], i3 = widx[n * 4 + 3];
    for (int c = threadIdx.x; c < DIM; c += 256) {
        float s = ldin(tok, i0 * DIM + c, f) + ldin(tok, i1 * DIM + c, f)
                + ldin(tok, i2 * DIM + c, f) + ldin(tok, i3 * DIM + c, f);
        xb[(long)n * DIM + c] = f2bf(s * 0.25f);
    }
}

// ---------------- edge prep ----------------
__global__ void count_kernel(const int* __restrict__ ei, const int* __restrict__ et,
                             int* __restrict__ cnt)
{
    int e = blockIdx.x * 256 + threadIdx.x;
    if (e >= NEDGE) return;
    int dst = ei[NEDGE + e];
    int r = et[e];
    atomicAdd(&cnt[dst * RREL + r], 1);
}

// R7: thread-coarsened scan, ~22 barriers.
__global__ __launch_bounds__(1024) void scan_kernel(const int* __restrict__ cnt,
                                                    int* __restrict__ offs, int n)
{
    const int CH = (n + 1023) >> 10;        // 40 for n=40960
    int tid = threadIdx.x;
    int base = tid * CH;
    int s = 0;
    for (int i = 0; i < CH; i++)
        if (base + i < n) s += cnt[base + i];
    __shared__ int buf[1024];
    buf[tid] = s;
    __syncthreads();
    for (int o = 1; o < 1024; o <<= 1) {
        int t = (tid >= o) ? buf[tid - o] : 0;
        __syncthreads();
        buf[tid] += t;
        __syncthreads();
    }
    int run = (tid == 0) ? 0 : buf[tid - 1];   // exclusive prefix of this chunk
    if (tid == 0) offs[0] = 0;
    for (int i = 0; i < CH; i++) {
        if (base + i < n) {
            run += cnt[base + i];
            offs[base + i + 1] = run;
        }
    }
}

__global__ void fill_kernel(const int* __restrict__ ei, const int* __restrict__ et,
                            const int* __restrict__ offs, int* __restrict__ cursor,
                            int* __restrict__ sorted)
{
    int e = blockIdx.x * 256 + threadIdx.x;
    if (e >= NEDGE) return;
    int src = ei[e];
    int dst = ei[NEDGE + e];
    int r = et[e];
    int seg = dst * RREL + r;
    int pos = offs[seg] + atomicAdd(&cursor[seg], 1);
    sorted[pos] = src;
}

// ---------------- segment aggregation (per node) ----------------
// R10 v2: 768 threads = 4 groups x 192 lanes (group = 3 full waves).
// Group g owns relation g (no serial r-loop). Each lane: 8B ushort4 chunk
// of the 768-col row; neighbor loop unrolled x4 with independent partials.
__global__ __launch_bounds__(768) void aggregate_kernel(
    const unsigned short* __restrict__ xsrc, long xstride,
    const int* __restrict__ offs, const int* __restrict__ sorted,
    unsigned short* __restrict__ A, int write_root)
{
    const int n = blockIdx.x;
    const int t = threadIdx.x;
    const int g = t / 192;                 // relation index
    const int l = t - g * 192;             // ushort4 chunk within row
    const long rs4 = xstride >> 2;         // row stride in ushort4
    const u16x4* __restrict__ xs4 = (const u16x4*)xsrc;
    u16x4* __restrict__ Ap = (u16x4*)A;
    const long baseQ = ((long)n * KBIG) >> 2;
    const int s0 = offs[n * RREL + g];
    const int s1 = offs[n * RREL + g + 1];
    const float inv = 1.0f / (float)max(s1 - s0, 1);
    float p0[4] = {0, 0, 0, 0}, p1[4] = {0, 0, 0, 0};
    float p2[4] = {0, 0, 0, 0}, p3[4] = {0, 0, 0, 0};
    int i = s0;
    for (; i + 3 < s1; i += 4) {
        int e0 = sorted[i], e1 = sorted[i + 1], e2 = sorted[i + 2], e3 = sorted[i + 3];
        u16x4 w0 = xs4[(long)e0 * rs4 + l];
        u16x4 w1 = xs4[(long)e1 * rs4 + l];
        u16x4 w2 = xs4[(long)e2 * rs4 + l];
        u16x4 w3 = xs4[(long)e3 * rs4 + l];
#pragma unroll
        for (int c = 0; c < 4; c++) {
            p0[c] += bf2f(w0[c]); p1[c] += bf2f(w1[c]);
            p2[c] += bf2f(w2[c]); p3[c] += bf2f(w3[c]);
        }
    }
    for (; i < s1; i++) {
        int e = sorted[i];
        u16x4 w = xs4[(long)e * rs4 + l];
#pragma unroll
        for (int c = 0; c < 4; c++) p0[c] += bf2f(w[c]);
    }
    u16x4 o;
#pragma unroll
    for (int c = 0; c < 4; c++)
        o[c] = f2bf(((p0[c] + p1[c]) + (p2[c] + p3[c])) * inv);
    Ap[baseQ + g * (DIM / 4) + l] = o;
    if (write_root && t < 192)
        Ap[baseQ + RREL * (DIM / 4) + t] = xs4[(long)n * rs4 + t];
}

// ---------------- transpose + cast raw -> bf16 (reads raw via ldin) ----
__global__ __launch_bounds__(256) void transpose_cast_kernel(
    const void* __restrict__ in, int Ncols,
    unsigned short* __restrict__ out, int outStride, int colOff,
    const int* __restrict__ flag)
{
    int f = *flag;
    __shared__ float t[32][33];
    int kt = blockIdx.x * 32, nt = blockIdx.y * 32;
    int lx = threadIdx.x & 31, ly = threadIdx.x >> 5;
    for (int i = 0; i < 4; i++)
        t[ly + i * 8][lx] = ldin(in, (long)(kt + ly + i * 8) * Ncols + nt + lx, f);
    __syncthreads();
    for (int i = 0; i < 4; i++)
        out[(long)(nt + ly + i * 8) * outStride + colOff + kt + lx] = f2bf(t[lx][ly + i * 8]);
}

// ---------------- MFMA GEMM: C = A (M,K) @ Bt^T, bf16 in, f32 acc --------
__global__ __launch_bounds__(256) void gemm_bt_kernel(
    const unsigned short* __restrict__ A, const unsigned short* __restrict__ Bt,
    int K, const float* __restrict__ bias, int relu,
    float* __restrict__ outF, long strideF,
    unsigned short* __restrict__ outB, long strideB)
{
    __shared__ __align__(16) unsigned short As[128 * 32];
    __shared__ __align__(16) unsigned short Bs[128 * 32];
    const int tid = threadIdx.x;
    const int lane = tid & 63, wv = tid >> 6;
    const int wr = wv >> 1, wc = wv & 1;
    const int lr = lane & 15, q = lane >> 4;
    const long m0 = (long)blockIdx.x * 128, n0 = (long)blockIdx.y * 128;

    f32x4 acc[4][4] = {};

    for (int kt = 0; kt < K; kt += 32) {
#pragma unroll
        for (int i = 0; i < 2; i++) {
            int chunk = i * 256 + tid;
            int row = chunk >> 2, kc = (chunk & 3) * 8;
            const unsigned short* ga = A + (m0 + row) * K + kt + kc;
            const unsigned short* gb = Bt + (n0 + row) * K + kt + kc;
            int ldsbase = (i * 256 + wv * 64) * 8;
            __builtin_amdgcn_global_load_lds(
                (const __attribute__((address_space(1))) void*)ga,
                (__attribute__((address_space(3))) void*)&As[ldsbase], 16, 0, 0);
            __builtin_amdgcn_global_load_lds(
                (const __attribute__((address_space(1))) void*)gb,
                (__attribute__((address_space(3))) void*)&Bs[ldsbase], 16, 0, 0);
        }
        __syncthreads();
        bf16x8 af[4], bfr[4];
#pragma unroll
        for (int i = 0; i < 4; i++)
            af[i] = *(const bf16x8*)&As[(wr * 64 + i * 16 + lr) * 32 + q * 8];
#pragma unroll
        for (int j = 0; j < 4; j++)
            bfr[j] = *(const bf16x8*)&Bs[(wc * 64 + j * 16 + lr) * 32 + q * 8];
#pragma unroll
        for (int i = 0; i < 4; i++)
#pragma unroll
            for (int j = 0; j < 4; j++)
                acc[i][j] = __builtin_amdgcn_mfma_f32_16x16x32_bf16(af[i], bfr[j], acc[i][j], 0, 0, 0);
        __syncthreads();
    }

#pragma unroll
    for (int i = 0; i < 4; i++) {
#pragma unroll
        for (int j = 0; j < 4; j++) {
            long col = n0 + wc * 64 + j * 16 + lr;
            float bv = bias ? bias[col] : 0.0f;
#pragma unroll
            for (int r = 0; r < 4; r++) {
                long row = m0 + wr * 64 + i * 16 + q * 4 + r;
                float v = acc[i][j][r] + bv;
                if (relu) v = fmaxf(v, 0.0f);
                if (outF) outF[row * strideF + col] = v;
                if (outB) outB[row * strideB + col] = f2bf(v);
            }
        }
    }
}

// ---------------- pooling (mean/max over words) + cc -> bf16 A3 + f32 evF ----
__global__ __launch_bounds__(256) void pool_cc_kernel(
    const float* __restrict__ C2, const void* __restrict__ tok,
    const int* __restrict__ csi, unsigned short* __restrict__ A3,
    float* __restrict__ evF, const int* __restrict__ flag)
{
    int f = *flag;
    int s = blockIdx.x;
    int b = s / EVI;
    long seq = csi[b];
    for (int c = threadIdx.x; c < DIM; c += 256) {
        float mx = -1e30f, sm = 0.0f;
        const float* col = C2 + (long)s * WORDS * DOUT + c;
        for (int w = 0; w < WORDS; w++) {
            float v = col[(long)w * DOUT];
            sm += v;
            mx = fmaxf(mx, v);
        }
        float mean = sm * (1.0f / WORDS);
        evF[(long)s * (2 * DOUT) + c] = mean;
        evF[(long)s * (2 * DOUT) + DOUT + c] = mx;
        A3[(long)s * KATT + c] = f2bf(ldin(tok, seq * LSEQ * DIM + c, f));
        A3[(long)s * KATT + DIM + c] = f2bf(mean);
        A3[(long)s * KATT + DIM + DOUT + c] = f2bf(mx);
    }
}

// ---------------- merged attention tail (R10) ----------------------------
// p = C3 @ w1 (per row), out1 = sigmoid(p), softmax over EVI, weighted ev,
// build A4 row. One block per batch element b.
__global__ __launch_bounds__(256) void att_finish_kernel(
    const float* __restrict__ C3, const void* __restrict__ w1,
    const float* __restrict__ evF, const void* __restrict__ ccls,
    float* __restrict__ out, unsigned short* __restrict__ A4,
    const int* __restrict__ flag)
{
    int f = *flag;
    int b = blockIdx.x;
    int t = threadIdx.x;
    __shared__ float red[256];
    __shared__ float a[EVI];
    __shared__ float psh[EVI];
    for (int e = 0; e < EVI; e++) {
        int s = b * EVI + e;
        float sum = 0.0f;
        for (int k = t; k < DOUT; k += 256)
            sum += C3[(long)s * DOUT + k] * ldin(w1, k, f);
        red[t] = sum;
        __syncthreads();
        for (int o = 128; o > 0; o >>= 1) {
            if (t < o) red[t] += red[t + o];
            __syncthreads();
        }
        if (t == 0) psh[e] = red[0];
        __syncthreads();
    }
    if (t < EVI) out[BN * NCLS + b * EVI + t] = 1.0f / (1.0f + __expf(-psh[t]));
    if (t == 0) {
        float m = -1e30f;
        for (int e = 0; e < EVI; e++) m = fmaxf(m, psh[e]);
        float ssum = 0.0f, ex[EVI];
        for (int e = 0; e < EVI; e++) { ex[e] = __expf(psh[e] - m); ssum += ex[e]; }
        for (int e = 0; e < EVI; e++) a[e] = ex[e] / ssum;
    }
    __syncthreads();
    for (int d = t; d < 2 * DOUT; d += 256) {
        float gg = 0.0f;
        for (int e = 0; e < EVI; e++)
            gg += a[e] * evF[(long)(b * EVI + e) * (2 * DOUT) + d];
        A4[(long)b * KATT + d] = f2bf(gg);
    }
    for (int c = t; c < DIM; c += 256)
        A4[(long)b * KATT + 2 * DOUT + c] = f2bf(ldin(ccls, (long)b * DIM + c, f));
}

// ---------------- final: lin2 + log_softmax (raw w2/b2 via ldin) -------
__global__ __launch_bounds__(256) void final_kernel(
    const float* __restrict__ C4, const void* __restrict__ w2,
    const void* __restrict__ bb, float* __restrict__ out,
    const int* __restrict__ flag)
{
    int f = *flag;
    int b = blockIdx.x;
    float s0 = 0.0f, s1 = 0.0f, s2 = 0.0f;
    for (int k = threadIdx.x; k < LH; k += 256) {
        float h = C4[(long)b * LH + k];
        s0 += h * ldin(w2, k * NCLS + 0, f);
        s1 += h * ldin(w2, k * NCLS + 1, f);
        s2 += h * ldin(w2, k * NCLS + 2, f);
    }
    __shared__ float r0[256], r1[256], r2[256];
    int t = threadIdx.x;
    r0[t] = s0; r1[t] = s1; r2[t] = s2;
    __syncthreads();
    for (int o = 128; o > 0; o >>= 1) {
        if (t < o) { r0[t] += r0[t + o]; r1[t] += r1[t + o]; r2[t] += r2[t + o]; }
        __syncthreads();
    }
    if (t == 0) {
        float l0 = r0[0] + ldin(bb, 0, f), l1 = r1[0] + ldin(bb, 1, f), l2 = r2[0] + ldin(bb, 2, f);
        float m = fmaxf(l0, fmaxf(l1, l2));
        float lse = logf(__expf(l0 - m) + __expf(l1 - m) + __expf(l2 - m)) + m;
        out[b * NCLS + 0] = l0 - lse;
        out[b * NCLS + 1] = l1 - lse;
        out[b * NCLS + 2] = l2 - lse;
    }
}

extern "C" void kernel_launch(void* const* d_in, const int* in_sizes, int n_in,
                              void* d_out, int out_size, void* d_ws, size_t ws_size,
                              hipStream_t stream)
{
    const void* tok      = d_in[0];
    const void* ccls_r   = d_in[1];
    const void* W_rel1_r = d_in[2];
    const void* W_root1_r= d_in[3];
    const void* b1_r     = d_in[4];
    const void* W_rel2_r = d_in[5];
    const void* W_root2_r= d_in[6];
    const void* b2_r     = d_in[7];
    const void* att_w0_r = d_in[8];
    const void* att_w1_r = d_in[9];
    const void* lin1_w_r = d_in[10];
    const void* lin1_b_r = d_in[11];
    const void* lin2_w_r = d_in[12];
    const void* lin2_b_r = d_in[13];
    const int* widx      = (const int*)d_in[14];
    const int* ei        = (const int*)d_in[15];
    const int* et        = (const int*)d_in[16];
    const int* csi       = (const int*)d_in[17];
    float* out           = (float*)d_out;

    char* ws = (char*)d_ws;
    size_t off = 0;
    auto alloc = [&](size_t bytes) { size_t o = off; off = (off + bytes + 255) & ~(size_t)255; return o; };

    int* flag   = (int*)(ws + alloc(256));
    float* b1F     = (float*)(ws + alloc((size_t)DIM * 4));
    float* b2F     = (float*)(ws + alloc((size_t)DOUT * 4));
    float* l1bF    = (float*)(ws + alloc((size_t)LH * 4));
    unsigned short* xb  = (unsigned short*)(ws + alloc((size_t)NNODE * DIM * 2));
    unsigned short* A1  = (unsigned short*)(ws + alloc((size_t)NNODE * KBIG * 2));
    unsigned short* X1  = (unsigned short*)(ws + alloc((size_t)NNODE * DOUT * 2));
    unsigned short* Wt1 = (unsigned short*)(ws + alloc((size_t)DIM * KBIG * 2));
    unsigned short* Wt2 = (unsigned short*)(ws + alloc((size_t)DIM * KBIG * 2));
    unsigned short* Wt3 = (unsigned short*)(ws + alloc((size_t)DOUT * KATT * 2));
    unsigned short* Wt4 = (unsigned short*)(ws + alloc((size_t)LH * KATT * 2));
    float* C2           = (float*)(ws + alloc((size_t)NNODE * DOUT * 4));
    unsigned short* A3  = (unsigned short*)(ws + alloc((size_t)384 * KATT * 2));
    float* C3           = (float*)(ws + alloc((size_t)384 * DOUT * 4));
    float* evF          = (float*)(ws + alloc((size_t)SEQS * 2 * DOUT * 4));
    unsigned short* A4  = (unsigned short*)(ws + alloc((size_t)128 * KATT * 2));
    float* C4           = (float*)(ws + alloc((size_t)128 * LH * 4));
    int* cnt            = (int*)(ws + alloc((size_t)2 * NNODE * RREL * 4));
    int* cursor         = cnt + NNODE * RREL;
    int* offs           = (int*)(ws + alloc((size_t)(NNODE * RREL + 1) * 4));
    int* sorted         = (int*)(ws + alloc((size_t)NEDGE * 4));
    (void)ws_size; (void)in_sizes; (void)n_in; (void)out_size;

    // dtype detect + canonicalize small f32-typed consumers (gemm bias ptrs)
    detect_kernel<<<1, 64, 0, stream>>>(W_rel1_r, flag);
    auto conv = [&](const void* src, float* dst, long n) {
        int grid = (int)min((n + 255) / 256, (long)2048);
        convert_kernel<<<grid, 256, 0, stream>>>(src, dst, n, flag);
    };
    conv(b1_r,     b1F,     DIM);
    conv(b2_r,     b2F,     DOUT);
    conv(lin1_b_r, l1bF,    LH);

    // edge prep
    hipMemsetAsync(cnt, 0, (size_t)2 * NNODE * RREL * 4, stream);
    count_kernel<<<NEDGE / 256, 256, 0, stream>>>(ei, et, cnt);
    scan_kernel<<<1, 1024, 0, stream>>>(cnt, offs, NNODE * RREL);
    fill_kernel<<<NEDGE / 256, 256, 0, stream>>>(ei, et, offs, cursor, sorted);

    // token gather
    gather_mean_kernel<<<NNODE, 256, 0, stream>>>(tok, widx, xb, flag);

    // weight transposes (raw -> bf16, B^T layout)
    transpose_cast_kernel<<<dim3(96, 24), 256, 0, stream>>>(W_rel1_r, DIM, Wt1, KBIG, 0, flag);
    transpose_cast_kernel<<<dim3(24, 24), 256, 0, stream>>>(W_root1_r, DIM, Wt1, KBIG, 4 * DIM, flag);
    transpose_cast_kernel<<<dim3(96, 24), 256, 0, stream>>>(W_rel2_r, DOUT, Wt2, KBIG, 0, flag);
    transpose_cast_kernel<<<dim3(24, 24), 256, 0, stream>>>(W_root2_r, DOUT, Wt2, KBIG, 4 * DIM, flag);
    transpose_cast_kernel<<<dim3(72, 24), 256, 0, stream>>>(att_w0_r, DOUT, Wt3, KATT, 0, flag);
    transpose_cast_kernel<<<dim3(72, 32), 256, 0, stream>>>(lin1_w_r, LH, Wt4, KATT, 0, flag);

    // layer 1: A1 = [agg_r(xb) | xb];  X1 = relu(A1 @ W1)
    aggregate_kernel<<<NNODE, 768, 0, stream>>>(xb, DIM, offs, sorted, A1, 1);
    gemm_bt_kernel<<<dim3(NNODE / 128, DIM / 128), 256, 0, stream>>>(
        A1, Wt1, KBIG, b1F, 1, nullptr, 0, X1, DOUT);

    // layer 2: A1 = [agg_r(X1) | X1];  C2 = relu(A1 @ W2)  (f32)
    aggregate_kernel<<<NNODE, 768, 0, stream>>>(X1, DOUT, offs, sorted, A1, 1);
    gemm_bt_kernel<<<dim3(NNODE / 128, DOUT / 128), 256, 0, stream>>>(
        A1, Wt2, KBIG, b2F, 1, C2, DOUT, nullptr, 0);

    // pooling + attention MLP (MFMA)
    pool_cc_kernel<<<SEQS, 256, 0, stream>>>(C2, tok, csi, A3, evF, flag);
    gemm_bt_kernel<<<dim3(3, DOUT / 128), 256, 0, stream>>>(
        A3, Wt3, KATT, nullptr, 1, C3, DOUT, nullptr, 0);
    att_finish_kernel<<<BN, 256, 0, stream>>>(C3, att_w1_r, evF, ccls_r, out, A4, flag);

    // classifier head (MFMA)
    gemm_bt_kernel<<<dim3(1, LH / 128), 256, 0, stream>>>(
        A4, Wt4, KATT, l1bF, 1, C4, LH, nullptr, 0);
    final_kernel<<<BN, 256, 0, stream>>>(C4, lin2_w_r, lin2_b_r, out, flag);
}

// Round 6
// 923.415 us; speedup vs baseline: 1.3215x; 1.0287x over previous
//
#include <hip/hip_runtime.h>
#include <hip/hip_fp16.h>

// Journal:
// R1-R4: correctness fights; R4 passed at 6543us (naive serial GEMMs).
// R5: MFMA gemm_bt everywhere: 6543 -> 1220us.
// R6: wave-parallel detect: 1220 -> 1072us. Matched prediction.
// R7: kill 10/13 converts + coarsen scan: -14us (miss; model wrong).
// R8/R9: aggregate v1 (LDS edges, 1 pass, x4 MLP): 1058 -> 955. Matched
//     mechanism (latency-bound gather), ~70% of predicted magnitude.
// R10: aggregate v2 (relation-parallel, 8B loads) + tail merge: 955 -> 950.
//     MISS: aggregates were already at floor after R8. Don't touch again.
// R11: budget says ~600 modeled vs 950 measured; prime suspects = big GEMMs
//     just under the 148us fillBuffer mask + launch overhead + scalar gather.
//     Package: (1) gemm BK=64 (half the barrier drains, same 2-phase
//     structure, bit-identical accumulation); (2) K-split A: root term read
//     directly from xb/X1, aggregate no longer copies root (A1 -> 3072 wide);
//     (3) gather_mean float4/u16x4 vectorized; (4) 6 transposes -> 1 batched
//     kernel, 3 converts -> 1. Predict 950 -> ~860. absmax unchanged.
//     If neutral: R12 perturbation probe for per-kernel timing.

#define BN 64
#define EVI 5
#define SEQS (BN * EVI)
#define LSEQ 256
#define DIM 768
#define WORDS 32
#define TPW 4
#define NNODE (BN * EVI * WORDS)   // 10240
#define NEDGE (NNODE * 16)         // 163840
#define RREL 4
#define DOUT 768
#define LH 1024
#define NCLS 3
#define KAGG (4 * DIM)             // 3072 (A1 width, rel part only)
#define KBIG (5 * DIM)             // 3840 (B-side K)
#define KATT (DIM + 2 * DOUT)      // 2304

typedef float f32x4 __attribute__((ext_vector_type(4)));
typedef __bf16 bf16x8 __attribute__((ext_vector_type(8)));
typedef unsigned short u16x4 __attribute__((ext_vector_type(4)));

__device__ inline unsigned short f2bf(float f) {
    union { float f; unsigned int u; } v; v.f = f;
    unsigned int u = v.u;
    unsigned int lsb = (u >> 16) & 1u;
    u += 0x7fffu + lsb;
    return (unsigned short)(u >> 16);
}
__device__ inline float bf2f(unsigned short h) {
    union { float f; unsigned int u; } v; v.u = ((unsigned int)h) << 16; return v.f;
}

// flag: 0 = f32, 1 = fp16, 2 = bf16 storage of "float32" inputs
__device__ inline float ldin(const void* p, long i, int f) {
    if (f == 1) return __half2float(((const __half*)p)[i]);
    if (f == 2) return bf2f(((const unsigned short*)p)[i]);
    return ((const float*)p)[i];
}

// ---------------- dtype detector (no-op safety; R3 showed flag=0) ----------
__global__ void detect_kernel(const void* w, int* flag) {
    const int lane = threadIdx.x;
    const unsigned int* u32 = (const unsigned int*)w;
    const unsigned short* u16 = (const unsigned short*)w;
    int tiny = 0;
    for (int i = lane; i < 2048; i += 64) {
        unsigned int b = u32[i];
        float f; __builtin_memcpy(&f, &b, 4);
        float a = fabsf(f);
        if (!(a > 1e-10f)) tiny++;
    }
    int band = 0;
    for (int i = lane; i < 4096; i += 64) {
        unsigned short h = u16[i];
        int e8 = (h >> 7) & 0xFF;
        if (h == 0 || (e8 >= 0x66 && e8 <= 0x86)) band++;
    }
#pragma unroll
    for (int o = 32; o > 0; o >>= 1) {
        tiny += __shfl_down(tiny, o);
        band += __shfl_down(band, o);
    }
    if (lane == 0) {
        if (tiny > 1024) { *flag = 1; return; }
        *flag = (band > 3900) ? 2 : 0;
    }
}

// ---------------- merged canonicalize: b1 | b2 | lin1_b ----------------
__global__ void convert3_kernel(const void* __restrict__ b1, const void* __restrict__ b2,
                                const void* __restrict__ l1b,
                                float* __restrict__ b1F, float* __restrict__ b2F,
                                float* __restrict__ l1bF, const int* __restrict__ flag)
{
    int f = *flag;
    int i = blockIdx.x * 256 + threadIdx.x;
    if (i < DIM) b1F[i] = ldin(b1, i, f);
    else if (i < 2 * DIM) b2F[i - DIM] = ldin(b2, i - DIM, f);
    else if (i < 2 * DIM + LH) l1bF[i - 2 * DIM] = ldin(l1b, i - 2 * DIM, f);
}

// ---------------- token gather + mean over TPW (R11: float4 vectorized) ----
__global__ __launch_bounds__(192) void gather_mean_kernel(
    const void* __restrict__ tok, const int* __restrict__ widx,
    unsigned short* __restrict__ xb, const int* __restrict__ flag)
{
    int f = *flag;
    int n = blockIdx.x;
    int t = threadIdx.x;                       // float4 chunk index, 192 = DIM/4
    long i0 = widx[n * 4 + 0], i1 = widx[n * 4 + 1];
    long i2 = widx[n * 4 + 2], i3 = widx[n * 4 + 3];
    u16x4 o;
    if (f == 0) {
        const f32x4* tf = (const f32x4*)tok;
        f32x4 a = tf[i0 * (DIM / 4) + t];
        f32x4 b = tf[i1 * (DIM / 4) + t];
        f32x4 c = tf[i2 * (DIM / 4) + t];
        f32x4 d = tf[i3 * (DIM / 4) + t];
#pragma unroll
        for (int c4 = 0; c4 < 4; c4++)
            o[c4] = f2bf((a[c4] + b[c4] + c[c4] + d[c4]) * 0.25f);
    } else {
#pragma unroll
        for (int c4 = 0; c4 < 4; c4++) {
            long c = (long)t * 4 + c4;
            float s = ldin(tok, i0 * DIM + c, f) + ldin(tok, i1 * DIM + c, f)
                    + ldin(tok, i2 * DIM + c, f) + ldin(tok, i3 * DIM + c, f);
            o[c4] = f2bf(s * 0.25f);
        }
    }
    ((u16x4*)xb)[(long)n * (DIM / 4) + t] = o;
}

// ---------------- edge prep ----------------
__global__ void count_kernel(const int* __restrict__ ei, const int* __restrict__ et,
                             int* __restrict__ cnt)
{
    int e = blockIdx.x * 256 + threadIdx.x;
    if (e >= NEDGE) return;
    int dst = ei[NEDGE + e];
    int r = et[e];
    atomicAdd(&cnt[dst * RREL + r], 1);
}

__global__ __launch_bounds__(1024) void scan_kernel(const int* __restrict__ cnt,
                                                    int* __restrict__ offs, int n)
{
    const int CH = (n + 1023) >> 10;
    int tid = threadIdx.x;
    int base = tid * CH;
    int s = 0;
    for (int i = 0; i < CH; i++)
        if (base + i < n) s += cnt[base + i];
    __shared__ int buf[1024];
    buf[tid] = s;
    __syncthreads();
    for (int o = 1; o < 1024; o <<= 1) {
        int t = (tid >= o) ? buf[tid - o] : 0;
        __syncthreads();
        buf[tid] += t;
        __syncthreads();
    }
    int run = (tid == 0) ? 0 : buf[tid - 1];
    if (tid == 0) offs[0] = 0;
    for (int i = 0; i < CH; i++) {
        if (base + i < n) {
            run += cnt[base + i];
            offs[base + i + 1] = run;
        }
    }
}

__global__ void fill_kernel(const int* __restrict__ ei, const int* __restrict__ et,
                            const int* __restrict__ offs, int* __restrict__ cursor,
                            int* __restrict__ sorted)
{
    int e = blockIdx.x * 256 + threadIdx.x;
    if (e >= NEDGE) return;
    int src = ei[e];
    int dst = ei[NEDGE + e];
    int r = et[e];
    int seg = dst * RREL + r;
    int pos = offs[seg] + atomicAdd(&cursor[seg], 1);
    sorted[pos] = src;
}

// ---------------- segment aggregation (per node, rel part only) -----------
// R10 structure; R11: no root copy (GEMM reads root directly from xsrc).
__global__ __launch_bounds__(768) void aggregate_kernel(
    const unsigned short* __restrict__ xsrc, long xstride,
    const int* __restrict__ offs, const int* __restrict__ sorted,
    unsigned short* __restrict__ A)
{
    const int n = blockIdx.x;
    const int t = threadIdx.x;
    const int g = t / 192;                 // relation index
    const int l = t - g * 192;             // ushort4 chunk within row
    const long rs4 = xstride >> 2;
    const u16x4* __restrict__ xs4 = (const u16x4*)xsrc;
    u16x4* __restrict__ Ap = (u16x4*)A;
    const long baseQ = ((long)n * KAGG) >> 2;
    const int s0 = offs[n * RREL + g];
    const int s1 = offs[n * RREL + g + 1];
    const float inv = 1.0f / (float)max(s1 - s0, 1);
    float p0[4] = {0, 0, 0, 0}, p1[4] = {0, 0, 0, 0};
    float p2[4] = {0, 0, 0, 0}, p3[4] = {0, 0, 0, 0};
    int i = s0;
    for (; i + 3 < s1; i += 4) {
        int e0 = sorted[i], e1 = sorted[i + 1], e2 = sorted[i + 2], e3 = sorted[i + 3];
        u16x4 w0 = xs4[(long)e0 * rs4 + l];
        u16x4 w1 = xs4[(long)e1 * rs4 + l];
        u16x4 w2 = xs4[(long)e2 * rs4 + l];
        u16x4 w3 = xs4[(long)e3 * rs4 + l];
#pragma unroll
        for (int c = 0; c < 4; c++) {
            p0[c] += bf2f(w0[c]); p1[c] += bf2f(w1[c]);
            p2[c] += bf2f(w2[c]); p3[c] += bf2f(w3[c]);
        }
    }
    for (; i < s1; i++) {
        int e = sorted[i];
        u16x4 w = xs4[(long)e * rs4 + l];
#pragma unroll
        for (int c = 0; c < 4; c++) p0[c] += bf2f(w[c]);
    }
    u16x4 o;
#pragma unroll
    for (int c = 0; c < 4; c++)
        o[c] = f2bf(((p0[c] + p1[c]) + (p2[c] + p3[c])) * inv);
    Ap[baseQ + g * (DIM / 4) + l] = o;
}

// ---------------- batched transpose + cast raw -> bf16 (R11: 6-in-1) ------
__global__ __launch_bounds__(256) void transpose_batch_kernel(
    const void* __restrict__ s0, const void* __restrict__ s1,
    const void* __restrict__ s2, const void* __restrict__ s3,
    const void* __restrict__ s4, const void* __restrict__ s5,
    unsigned short* __restrict__ Wt1, unsigned short* __restrict__ Wt2,
    unsigned short* __restrict__ Wt3, unsigned short* __restrict__ Wt4,
    const int* __restrict__ flag)
{
    int f = *flag;
    int b = blockIdx.x;
    const void* src; unsigned short* dst;
    int Ncols, ostride, coff, ktiles, rel;
    if (b < 2304)      { src = s0; dst = Wt1; Ncols = DIM;  ostride = KBIG; coff = 0;    ktiles = 96; rel = b; }
    else if (b < 2880) { src = s1; dst = Wt1; Ncols = DIM;  ostride = KBIG; coff = KAGG; ktiles = 24; rel = b - 2304; }
    else if (b < 5184) { src = s2; dst = Wt2; Ncols = DOUT; ostride = KBIG; coff = 0;    ktiles = 96; rel = b - 2880; }
    else if (b < 5760) { src = s3; dst = Wt2; Ncols = DOUT; ostride = KBIG; coff = KAGG; ktiles = 24; rel = b - 5184; }
    else if (b < 7488) { src = s4; dst = Wt3; Ncols = DOUT; ostride = KATT; coff = 0;    ktiles = 72; rel = b - 5760; }
    else               { src = s5; dst = Wt4; Ncols = LH;   ostride = KATT; coff = 0;    ktiles = 72; rel = b - 7488; }
    int kt = (rel % ktiles) * 32, nt = (rel / ktiles) * 32;
    __shared__ float t[32][33];
    int lx = threadIdx.x & 31, ly = threadIdx.x >> 5;
    for (int i = 0; i < 4; i++)
        t[ly + i * 8][lx] = ldin(src, (long)(kt + ly + i * 8) * Ncols + nt + lx, f);
    __syncthreads();
    for (int i = 0; i < 4; i++)
        dst[(long)(nt + ly + i * 8) * ostride + coff + kt + lx] = f2bf(t[lx][ly + i * 8]);
}

// ---------------- MFMA GEMM: C = [A | Ar] (M,K) @ Bt^T, bf16, f32 acc -----
// R11: BK=64 (half the barriers), K-split A source (A is ksplit wide; columns
// ksplit..K-1 come from Ar, (K-ksplit) wide). Accumulation order identical
// to BK=32 version (s=0 then s=1 per 64-step == kt, kt+32).
__global__ __launch_bounds__(256) void gemm_bt_kernel(
    const unsigned short* __restrict__ A, const unsigned short* __restrict__ Ar,
    int K, int ksplit, const unsigned short* __restrict__ Bt,
    const float* __restrict__ bias, int relu,
    float* __restrict__ outF, long strideF,
    unsigned short* __restrict__ outB, long strideB)
{
    __shared__ __align__(16) unsigned short As[128 * 64];
    __shared__ __align__(16) unsigned short Bs[128 * 64];
    const int tid = threadIdx.x;
    const int lane = tid & 63, wv = tid >> 6;
    const int wr = wv >> 1, wc = wv & 1;
    const int lr = lane & 15, q = lane >> 4;
    const long m0 = (long)blockIdx.x * 128, n0 = (long)blockIdx.y * 128;

    f32x4 acc[4][4] = {};

    for (int kt = 0; kt < K; kt += 64) {
        const unsigned short* Ab;
        long sA;
        if (kt < ksplit) { Ab = A + kt; sA = ksplit; }
        else             { Ab = Ar + (kt - ksplit); sA = K - ksplit; }
#pragma unroll
        for (int i = 0; i < 4; i++) {
            int chunk = i * 256 + tid;         // 0..1023 chunks of 16B
            int row = chunk >> 3, kc = (chunk & 7) * 8;
            const unsigned short* ga = Ab + (m0 + row) * sA + kc;
            const unsigned short* gb = Bt + (n0 + row) * K + kt + kc;
            __builtin_amdgcn_global_load_lds(
                (const __attribute__((address_space(1))) void*)ga,
                (__attribute__((address_space(3))) void*)&As[chunk * 8], 16, 0, 0);
            __builtin_amdgcn_global_load_lds(
                (const __attribute__((address_space(1))) void*)gb,
                (__attribute__((address_space(3))) void*)&Bs[chunk * 8], 16, 0, 0);
        }
        __syncthreads();
        bf16x8 af[2][4], bfr[2][4];
#pragma unroll
        for (int s = 0; s < 2; s++) {
#pragma unroll
            for (int i = 0; i < 4; i++)
                af[s][i] = *(const bf16x8*)&As[(wr * 64 + i * 16 + lr) * 64 + s * 32 + q * 8];
#pragma unroll
            for (int j = 0; j < 4; j++)
                bfr[s][j] = *(const bf16x8*)&Bs[(wc * 64 + j * 16 + lr) * 64 + s * 32 + q * 8];
        }
#pragma unroll
        for (int s = 0; s < 2; s++)
#pragma unroll
            for (int i = 0; i < 4; i++)
#pragma unroll
                for (int j = 0; j < 4; j++)
                    acc[i][j] = __builtin_amdgcn_mfma_f32_16x16x32_bf16(af[s][i], bfr[s][j], acc[i][j], 0, 0, 0);
        __syncthreads();
    }

#pragma unroll
    for (int i = 0; i < 4; i++) {
#pragma unroll
        for (int j = 0; j < 4; j++) {
            long col = n0 + wc * 64 + j * 16 + lr;
            float bv = bias ? bias[col] : 0.0f;
#pragma unroll
            for (int r = 0; r < 4; r++) {
                long row = m0 + wr * 64 + i * 16 + q * 4 + r;
                float v = acc[i][j][r] + bv;
                if (relu) v = fmaxf(v, 0.0f);
                if (outF) outF[row * strideF + col] = v;
                if (outB) outB[row * strideB + col] = f2bf(v);
            }
        }
    }
}

// ---------------- pooling (mean/max over words) + cc -> bf16 A3 + f32 evF ----
__global__ __launch_bounds__(256) void pool_cc_kernel(
    const float* __restrict__ C2, const void* __restrict__ tok,
    const int* __restrict__ csi, unsigned short* __restrict__ A3,
    float* __restrict__ evF, const int* __restrict__ flag)
{
    int f = *flag;
    int s = blockIdx.x;
    int b = s / EVI;
    long seq = csi[b];
    for (int c = threadIdx.x; c < DIM; c += 256) {
        float mx = -1e30f, sm = 0.0f;
        const float* col = C2 + (long)s * WORDS * DOUT + c;
        for (int w = 0; w < WORDS; w++) {
            float v = col[(long)w * DOUT];
            sm += v;
            mx = fmaxf(mx, v);
        }
        float mean = sm * (1.0f / WORDS);
        evF[(long)s * (2 * DOUT) + c] = mean;
        evF[(long)s * (2 * DOUT) + DOUT + c] = mx;
        A3[(long)s * KATT + c] = f2bf(ldin(tok, seq * LSEQ * DIM + c, f));
        A3[(long)s * KATT + DIM + c] = f2bf(mean);
        A3[(long)s * KATT + DIM + DOUT + c] = f2bf(mx);
    }
}

// ---------------- merged attention tail ----------------------------------
__global__ __launch_bounds__(256) void att_finish_kernel(
    const float* __restrict__ C3, const void* __restrict__ w1,
    const float* __restrict__ evF, const void* __restrict__ ccls,
    float* __restrict__ out, unsigned short* __restrict__ A4,
    const int* __restrict__ flag)
{
    int f = *flag;
    int b = blockIdx.x;
    int t = threadIdx.x;
    __shared__ float red[256];
    __shared__ float a[EVI];
    __shared__ float psh[EVI];
    for (int e = 0; e < EVI; e++) {
        int s = b * EVI + e;
        float sum = 0.0f;
        for (int k = t; k < DOUT; k += 256)
            sum += C3[(long)s * DOUT + k] * ldin(w1, k, f);
        red[t] = sum;
        __syncthreads();
        for (int o = 128; o > 0; o >>= 1) {
            if (t < o) red[t] += red[t + o];
            __syncthreads();
        }
        if (t == 0) psh[e] = red[0];
        __syncthreads();
    }
    if (t < EVI) out[BN * NCLS + b * EVI + t] = 1.0f / (1.0f + __expf(-psh[t]));
    if (t == 0) {
        float m = -1e30f;
        for (int e = 0; e < EVI; e++) m = fmaxf(m, psh[e]);
        float ssum = 0.0f, ex[EVI];
        for (int e = 0; e < EVI; e++) { ex[e] = __expf(psh[e] - m); ssum += ex[e]; }
        for (int e = 0; e < EVI; e++) a[e] = ex[e] / ssum;
    }
    __syncthreads();
    for (int d = t; d < 2 * DOUT; d += 256) {
        float gg = 0.0f;
        for (int e = 0; e < EVI; e++)
            gg += a[e] * evF[(long)(b * EVI + e) * (2 * DOUT) + d];
        A4[(long)b * KATT + d] = f2bf(gg);
    }
    for (int c = t; c < DIM; c += 256)
        A4[(long)b * KATT + 2 * DOUT + c] = f2bf(ldin(ccls, (long)b * DIM + c, f));
}

// ---------------- final: lin2 + log_softmax ----------------
__global__ __launch_bounds__(256) void final_kernel(
    const float* __restrict__ C4, const void* __restrict__ w2,
    const void* __restrict__ bb, float* __restrict__ out,
    const int* __restrict__ flag)
{
    int f = *flag;
    int b = blockIdx.x;
    float s0 = 0.0f, s1 = 0.0f, s2 = 0.0f;
    for (int k = threadIdx.x; k < LH; k += 256) {
        float h = C4[(long)b * LH + k];
        s0 += h * ldin(w2, k * NCLS + 0, f);
        s1 += h * ldin(w2, k * NCLS + 1, f);
        s2 += h * ldin(w2, k * NCLS + 2, f);
    }
    __shared__ float r0[256], r1[256], r2[256];
    int t = threadIdx.x;
    r0[t] = s0; r1[t] = s1; r2[t] = s2;
    __syncthreads();
    for (int o = 128; o > 0; o >>= 1) {
        if (t < o) { r0[t] += r0[t + o]; r1[t] += r1[t + o]; r2[t] += r2[t + o]; }
        __syncthreads();
    }
    if (t == 0) {
        float l0 = r0[0] + ldin(bb, 0, f), l1 = r1[0] + ldin(bb, 1, f), l2 = r2[0] + ldin(bb, 2, f);
        float m = fmaxf(l0, fmaxf(l1, l2));
        float lse = logf(__expf(l0 - m) + __expf(l1 - m) + __expf(l2 - m)) + m;
        out[b * NCLS + 0] = l0 - lse;
        out[b * NCLS + 1] = l1 - lse;
        out[b * NCLS + 2] = l2 - lse;
    }
}

extern "C" void kernel_launch(void* const* d_in, const int* in_sizes, int n_in,
                              void* d_out, int out_size, void* d_ws, size_t ws_size,
                              hipStream_t stream)
{
    const void* tok      = d_in[0];
    const void* ccls_r   = d_in[1];
    const void* W_rel1_r = d_in[2];
    const void* W_root1_r= d_in[3];
    const void* b1_r     = d_in[4];
    const void* W_rel2_r = d_in[5];
    const void* W_root2_r= d_in[6];
    const void* b2_r     = d_in[7];
    const void* att_w0_r = d_in[8];
    const void* att_w1_r = d_in[9];
    const void* lin1_w_r = d_in[10];
    const void* lin1_b_r = d_in[11];
    const void* lin2_w_r = d_in[12];
    const void* lin2_b_r = d_in[13];
    const int* widx      = (const int*)d_in[14];
    const int* ei        = (const int*)d_in[15];
    const int* et        = (const int*)d_in[16];
    const int* csi       = (const int*)d_in[17];
    float* out           = (float*)d_out;

    char* ws = (char*)d_ws;
    size_t off = 0;
    auto alloc = [&](size_t bytes) { size_t o = off; off = (off + bytes + 255) & ~(size_t)255; return o; };

    int* flag   = (int*)(ws + alloc(256));
    float* b1F     = (float*)(ws + alloc((size_t)DIM * 4));
    float* b2F     = (float*)(ws + alloc((size_t)DOUT * 4));
    float* l1bF    = (float*)(ws + alloc((size_t)LH * 4));
    unsigned short* xb  = (unsigned short*)(ws + alloc((size_t)NNODE * DIM * 2));
    unsigned short* A1  = (unsigned short*)(ws + alloc((size_t)NNODE * KAGG * 2));
    unsigned short* X1  = (unsigned short*)(ws + alloc((size_t)NNODE * DOUT * 2));
    unsigned short* Wt1 = (unsigned short*)(ws + alloc((size_t)DIM * KBIG * 2));
    unsigned short* Wt2 = (unsigned short*)(ws + alloc((size_t)DIM * KBIG * 2));
    unsigned short* Wt3 = (unsigned short*)(ws + alloc((size_t)DOUT * KATT * 2));
    unsigned short* Wt4 = (unsigned short*)(ws + alloc((size_t)LH * KATT * 2));
    float* C2           = (float*)(ws + alloc((size_t)NNODE * DOUT * 4));
    unsigned short* A3  = (unsigned short*)(ws + alloc((size_t)384 * KATT * 2));
    float* C3           = (float*)(ws + alloc((size_t)384 * DOUT * 4));
    float* evF          = (float*)(ws + alloc((size_t)SEQS * 2 * DOUT * 4));
    unsigned short* A4  = (unsigned short*)(ws + alloc((size_t)128 * KATT * 2));
    float* C4           = (float*)(ws + alloc((size_t)128 * LH * 4));
    int* cnt            = (int*)(ws + alloc((size_t)2 * NNODE * RREL * 4));
    int* cursor         = cnt + NNODE * RREL;
    int* offs           = (int*)(ws + alloc((size_t)(NNODE * RREL + 1) * 4));
    int* sorted         = (int*)(ws + alloc((size_t)NEDGE * 4));
    (void)ws_size; (void)in_sizes; (void)n_in; (void)out_size;

    // dtype detect + merged small converts
    detect_kernel<<<1, 64, 0, stream>>>(W_rel1_r, flag);
    convert3_kernel<<<(2 * DIM + LH + 255) / 256, 256, 0, stream>>>(
        b1_r, b2_r, lin1_b_r, b1F, b2F, l1bF, flag);

    // edge prep
    hipMemsetAsync(cnt, 0, (size_t)2 * NNODE * RREL * 4, stream);
    count_kernel<<<NEDGE / 256, 256, 0, stream>>>(ei, et, cnt);
    scan_kernel<<<1, 1024, 0, stream>>>(cnt, offs, NNODE * RREL);
    fill_kernel<<<NEDGE / 256, 256, 0, stream>>>(ei, et, offs, cursor, sorted);

    // token gather (vectorized)
    gather_mean_kernel<<<NNODE, 192, 0, stream>>>(tok, widx, xb, flag);

    // weight transposes, batched (raw -> bf16, B^T layout)
    transpose_batch_kernel<<<9792, 256, 0, stream>>>(
        W_rel1_r, W_root1_r, W_rel2_r, W_root2_r, att_w0_r, lin1_w_r,
        Wt1, Wt2, Wt3, Wt4, flag);

    // layer 1: A1 = agg_r(xb); X1 = relu([A1|xb] @ W1)
    aggregate_kernel<<<NNODE, 768, 0, stream>>>(xb, DIM, offs, sorted, A1);
    gemm_bt_kernel<<<dim3(NNODE / 128, DIM / 128), 256, 0, stream>>>(
        A1, xb, KBIG, KAGG, Wt1, b1F, 1, nullptr, 0, X1, DOUT);

    // layer 2: A1 = agg_r(X1); C2 = relu([A1|X1] @ W2)  (f32)
    aggregate_kernel<<<NNODE, 768, 0, stream>>>(X1, DOUT, offs, sorted, A1);
    gemm_bt_kernel<<<dim3(NNODE / 128, DOUT / 128), 256, 0, stream>>>(
        A1, X1, KBIG, KAGG, Wt2, b2F, 1, C2, DOUT, nullptr, 0);

    // pooling + attention MLP (MFMA)
    pool_cc_kernel<<<SEQS, 256, 0, stream>>>(C2, tok, csi, A3, evF, flag);
    gemm_bt_kernel<<<dim3(3, DOUT / 128), 256, 0, stream>>>(
        A3, nullptr, KATT, KATT, Wt3, nullptr, 1, C3, DOUT, nullptr, 0);
    att_finish_kernel<<<BN, 256, 0, stream>>>(C3, att_w1_r, evF, ccls_r, out, A4, flag);

    // classifier head (MFMA)
    gemm_bt_kernel<<<dim3(1, LH / 128), 256, 0, stream>>>(
        A4, nullptr, KATT, KATT, Wt4, l1bF, 1, C4, LH, nullptr, 0);
    final_kernel<<<BN, 256, 0, stream>>>(C4, lin2_w_r, lin2_b_r, out, flag);
}